// Round 5
// baseline (5809.339 us; speedup 1.0000x reference)
//
#include <hip/hip_runtime.h>

#define KU 512
#define NB 32
#define NT 64
#define TIL 16
#define SLOTS 16
#define NBMAX 40

// ---- ws float offsets ----
#define N_PONG   (KU * NB * 90)
#define OFF_WHB  (N_PONG)                      // [3][90][92] gate-major Wh_rnn
#define OFF_SYLO (OFF_WHB + 3 * 90 * 92)       // W_sync[0:90]^T   [90][92]
#define OFF_SYMID (OFF_SYLO + 90 * 92)         // W_sync[90:180]^T [90][92]
#define OFF_AGG  (OFF_SYMID + 90 * 92)         // W_agg^T          [90][92]
#define OFF_WIR  (OFF_AGG + 90 * 92)           // Wi_rnn^T         [270][92]
#define OFF_WPR  (OFF_WIR + 270 * 92)          // W_prop^T         [90][180]
#define OFF_WIS  (OFF_WPR + 90 * 180)          // Wi_self^T        [270][92]
#define OFF_WHS  (OFF_WIS + 270 * 92)          // Wh_self^T        [270][92]
#define OFF_CEB  (OFF_WHS + 270 * 92)          // ce_sync+b_sync   [512][90]
#define OFF_GI0  (OFF_CEB + KU * 90)           // gi0 [272]
#define OFF_ABUF (OFF_GI0 + 272)               // [96][92]: nsy | pvec | reflec per batch

struct __attribute__((aligned(4))) f3v { float x, y, z; };

__device__ __forceinline__ float sigf(float x) { return 1.0f / (1.0f + __expf(-x)); }
__device__ __forceinline__ float tanhf_(float x) {
    float e = __expf(2.0f * x);
    return 1.0f - 2.0f / (e + 1.0f);
}
__device__ __forceinline__ float dot4(float4 a, float4 b) {
    return a.x * b.x + a.y * b.y + a.z * b.z + a.w * b.w;
}
#define WAVE_SYNC() { asm volatile("s_waitcnt lgkmcnt(0)" ::: "memory"); __builtin_amdgcn_sched_barrier(0); }

// ============ prep: transposed/padded weights + ce_sync + gi0 ============
__global__ void skt_prep(const float* __restrict__ concept_emb, const float* __restrict__ W_sync,
                         const float* __restrict__ b_sync, const float* __restrict__ W_agg,
                         const float* __restrict__ W_prop, const float* __restrict__ Wi_rnn,
                         const float* __restrict__ Wh_rnn, const float* __restrict__ Wi_self,
                         const float* __restrict__ Wh_self, const float* __restrict__ bi_rnn,
                         const float* __restrict__ b_agg, float* __restrict__ ws) {
    const int blk = blockIdx.x, tid = threadIdx.x;
    if (blk < 128) {                       // ce_syncB[512][90]
        for (int rr = 0; rr < 4; ++rr) {
            const int k = blk * 4 + rr;
            if (tid < 90) {
                float acc = b_sync[tid];
                for (int kk = 0; kk < 90; ++kk)
                    acc += concept_emb[k * 90 + kk] * W_sync[(180 + kk) * 90 + tid];
                ws[OFF_CEB + k * 90 + tid] = acc;
            }
        }
    } else if (blk < 137) {                // WisT[270][92]
        const int c0 = (blk - 128) * 30;
        for (int rr = 0; rr < 30; ++rr) {
            const int c = c0 + rr;
            if (tid < 92) ws[OFF_WIS + c * 92 + tid] = (tid < 90) ? Wi_self[tid * 270 + c] : 0.f;
        }
    } else if (blk < 146) {                // WhsT[270][92]
        const int c0 = (blk - 137) * 30;
        for (int rr = 0; rr < 30; ++rr) {
            const int c = c0 + rr;
            if (tid < 92) ws[OFF_WHS + c * 92 + tid] = (tid < 90) ? Wh_self[tid * 270 + c] : 0.f;
        }
    } else if (blk < 155) {                // WirT[270][92]
        const int c0 = (blk - 146) * 30;
        for (int rr = 0; rr < 30; ++rr) {
            const int c = c0 + rr;
            if (tid < 92) ws[OFF_WIR + c * 92 + tid] = (tid < 90) ? Wi_rnn[tid * 270 + c] : 0.f;
        }
    } else if (blk < 158) {                // WsyT_lo[90][92]
        const int m0 = (blk - 155) * 30;
        for (int rr = 0; rr < 30; ++rr) {
            const int m = m0 + rr;
            if (tid < 92) ws[OFF_SYLO + m * 92 + tid] = (tid < 90) ? W_sync[tid * 90 + m] : 0.f;
        }
    } else if (blk < 161) {                // WsyT_mid[90][92]
        const int m0 = (blk - 158) * 30;
        for (int rr = 0; rr < 30; ++rr) {
            const int m = m0 + rr;
            if (tid < 92) ws[OFF_SYMID + m * 92 + tid] = (tid < 90) ? W_sync[(90 + tid) * 90 + m] : 0.f;
        }
    } else if (blk < 164) {                // WaggT[90][92]
        const int m0 = (blk - 161) * 30;
        for (int rr = 0; rr < 30; ++rr) {
            const int m = m0 + rr;
            if (tid < 92) ws[OFF_AGG + m * 92 + tid] = (tid < 90) ? W_agg[tid * 90 + m] : 0.f;
        }
    } else if (blk < 167) {                // WprT[90][180]
        const int m0 = (blk - 164) * 30;
        for (int rr = 0; rr < 30; ++rr) {
            const int m = m0 + rr;
            if (tid < 180) ws[OFF_WPR + m * 180 + tid] = W_prop[tid * 90 + m];
        }
    } else if (blk < 176) {                // WhB[3][90][92] gate-major
        const int k0 = (blk - 167) * 10;
        for (int rr = 0; rr < 10; ++rr) {
            const int k = k0 + rr;
            for (int i = tid; i < 276; i += 256) {
                const int g = i / 92, m = i - g * 92;
                ws[OFF_WHB + (size_t)g * 90 * 92 + k * 92 + m] =
                    (m < 90) ? Wh_rnn[k * 270 + g * 90 + m] : 0.f;
            }
        }
    } else if (blk == 176) {               // gi0[272]
        for (int c = tid; c < 272; c += 256) {
            float acc = 0.f;
            if (c < 270) {
                acc = bi_rnn[c];
                for (int kk = 0; kk < 90; ++kk)
                    acc += fmaxf(b_agg[kk], 0.f) * Wi_rnn[kk * 270 + c];
            }
            ws[OFF_GI0 + c] = acc;
        }
    }
}

// ============ K1: per-batch self GRU, nsync, pvec, reflec ============
__global__ __launch_bounds__(320, 1) void skt_batch(
    const int* __restrict__ qs, const int* __restrict__ as_,
    const float* __restrict__ response_emb, const float* __restrict__ concept_emb,
    const float* __restrict__ nb_adj, const float* __restrict__ bi_self,
    const float* __restrict__ bh_self, const float* __restrict__ b_prop,
    float* __restrict__ ws, const float* __restrict__ stIn, int t) {
    __shared__ alignas(16) float re[92], ssv[92], ceq[92], nsv[92], xprop[184];
    __shared__ alignas(16) float giA[272], ghA[272];
    __shared__ alignas(16) float nsyL[92], pvL[92];
    __shared__ alignas(16) float hnb[NBMAX][92];
    __shared__ alignas(16) float rfp[3][92];
    __shared__ float nbw[NBMAX];
    __shared__ int nblist[NBMAX];
    __shared__ int nnbS;

    const int tid = threadIdx.x;
    const int b = blockIdx.x;
    const int q = qs[b * NT + t], a = as_[b * NT + t];

    // phase 1: vectors + neighbor scan
    if (tid < 90) {
        re[tid] = response_emb[(size_t)a * 90 + tid];
        ssv[tid] = stIn[((size_t)(b * KU + q)) * 90 + tid];
        ceq[tid] = concept_emb[(size_t)q * 90 + tid];
    } else if (tid < 92) { re[tid] = 0.f; ssv[tid] = 0.f; ceq[tid] = 0.f; nsv[tid] = 0.f; }
    if (tid >= 256) {
        const int lane = tid - 256;
        int base = 0;
        for (int ch = 0; ch < 8; ++ch) {
            const int kp = ch * 64 + lane;
            const float nv = nb_adj[(size_t)q * KU + kp];
            const unsigned long long mb = __ballot(nv != 0.f);
            const int idx = base + (int)__popcll(mb & ((1ull << lane) - 1ull));
            if (nv != 0.f && idx < NBMAX) { nblist[idx] = kp; nbw[idx] = nv; }
            base += (int)__popcll(mb);
        }
        if (lane == 0) nnbS = (base < NBMAX) ? base : NBMAX;
    }
    __syncthreads();
    // phase 2: self-GRU matvecs
    if (tid < 270) {
        float a1 = bi_self[tid], a2 = bh_self[tid];
        const float4* w1 = (const float4*)(ws + OFF_WIS + (size_t)tid * 92);
        const float4* w2 = (const float4*)(ws + OFF_WHS + (size_t)tid * 92);
        const float4* rv = (const float4*)re;
        const float4* sv4 = (const float4*)ssv;
#pragma unroll 4
        for (int p = 0; p < 23; ++p) { a1 += dot4(rv[p], w1[p]); a2 += dot4(sv4[p], w2[p]); }
        giA[tid] = a1; ghA[tid] = a2;
    }
    __syncthreads();
    // phase 3: gates -> nsv,xprop (tid<90) | stage hnb (tid>=92)
    if (tid < 90) {
        const float r = sigf(giA[tid] + ghA[tid]);
        const float z = sigf(giA[90 + tid] + ghA[90 + tid]);
        const float g = tanhf_(giA[180 + tid] + r * ghA[180 + tid]);
        const float ns = (1.f - z) * g + z * ssv[tid];
        nsv[tid] = ns;
        xprop[tid] = ns - ssv[tid];
        xprop[90 + tid] = ceq[tid];
    } else if (tid >= 92) {
        const int nnb = nnbS;
        const int nnb4 = (nnb + 3) & ~3;
        for (int i = tid - 92; i < nnb4 * 46; i += 228) {
            const int j = i / 46, c2 = i - j * 46;
            float2 v = make_float2(0.f, 0.f);
            if (j < nnb && c2 < 45)
                v = ((const float2*)(stIn + ((size_t)(b * KU + nblist[j])) * 90))[c2];
            ((float2*)&hnb[j][0])[c2] = v;
        }
    }
    __syncthreads();
    // phase 4: nsync (tid<90) | pvec (90<=tid<180)
    if (tid < 90) {
        const float4* wm = (const float4*)(ws + OFF_SYMID + (size_t)tid * 92);
        const float4* nv4 = (const float4*)nsv;
        float d = 0.f;
#pragma unroll 4
        for (int p = 0; p < 23; ++p) d += dot4(nv4[p], wm[p]);
        nsyL[tid] = d;
    } else if (tid < 180) {
        const int m = tid - 90;
        const float4* wp = (const float4*)(ws + OFF_WPR + (size_t)m * 180);
        const float4* xp = (const float4*)xprop;
        float d = b_prop[m];
#pragma unroll 5
        for (int p = 0; p < 45; ++p) d += dot4(xp[p], wp[p]);
        pvL[m] = fmaxf(d, 0.f);
    }
    __syncthreads();
    // phase 5: reflec partials, 3 groups of 90
    if (tid < 270) {
        const int g = (tid >= 180) ? 2 : ((tid >= 90) ? 1 : 0);
        const int m = tid - g * 90;
        const int nnb = nnbS;
        const float nsym = nsyL[m];
        const float4* wrow = (const float4*)(ws + OFF_SYLO + (size_t)m * 92);
        float racc = 0.f;
        for (int j = g; j < nnb; j += 3) {
            const float4* hj = (const float4*)&hnb[j][0];
            float d = 0.f;
#pragma unroll 4
            for (int p = 0; p < 23; ++p) d += dot4(hj[p], wrow[p]);
            racc += nbw[j] * fmaxf(nsym + ws[OFF_CEB + (size_t)nblist[j] * 90 + m] + d, 0.f);
        }
        rfp[g][m] = racc;
    }
    __syncthreads();
    // phase 6: ABUF
    if (tid < 90) {
        ws[OFF_ABUF + (size_t)b * 92 + tid] = nsyL[tid];
        ws[OFF_ABUF + (size_t)(32 + b) * 92 + tid] = pvL[tid];
        ws[OFF_ABUF + (size_t)(64 + b) * 92 + tid] = rfp[0][tid] + rfp[1][tid] + rfp[2][tid];
    }
}

// ============ K2: 16-row tile, 256 thr, ~37 KB LDS -> 4 blocks/CU ============
__global__ __launch_bounds__(256, 4) void skt_tile(
    const int* __restrict__ qs, const float* __restrict__ nb_adj,
    const float* __restrict__ succ_adj, const float* __restrict__ bi_rnn,
    const float* __restrict__ bh_rnn, const float* __restrict__ b_agg,
    const float* __restrict__ W_out, const float* __restrict__ b_out,
    float* __restrict__ ws, const float* __restrict__ stIn, float* __restrict__ stOut,
    float* __restrict__ out, int t) {
    __shared__ alignas(16) float hT[90 * 20];      // transposed states (GEMM A), pad 16->20
    __shared__ alignas(16) float hR[TIL * 92];     // row-major states
    __shared__ alignas(16) float giL[SLOTS * 273];
    __shared__ alignas(16) float gi0L[273], biL[273];
    __shared__ alignas(16) float nsyL[92], pvL[92], rfL[92], baggL[92], woutL[92];
    __shared__ alignas(16) float actb[4][92], infb[4][92];
    __shared__ float nbvL[TIL], svL[TIL];
    __shared__ int rowslotS[TIL], listS[TIL];
    __shared__ int nactS;

    const int tid = threadIdx.x;
    const int bb = blockIdx.x >> 5;
    const int k0 = (blockIdx.x & 31) * TIL;
    const int q = qs[bb * NT + t];

    // ---------- stage ----------
    if (tid < 192) {
        for (int idx = tid; idx < 45 * TIL; idx += 192) {   // 720 float2 loads
            const int row = idx & 15, c2 = idx >> 4;
            const float2 v = ((const float2*)(stIn + ((size_t)(bb * KU + k0 + row)) * 90))[c2];
            ((float2*)&hR[row * 92])[c2] = v;
            hT[(2 * c2) * 20 + row] = v.x;
            hT[(2 * c2 + 1) * 20 + row] = v.y;
        }
        if (tid < 92) {
            const int m = tid;
            nsyL[m] = ws[OFF_ABUF + (size_t)bb * 92 + m];
            pvL[m] = ws[OFF_ABUF + (size_t)(32 + bb) * 92 + m];
            rfL[m] = ws[OFF_ABUF + (size_t)(64 + bb) * 92 + m];
            baggL[m] = (m < 90) ? b_agg[m] : 0.f;
            woutL[m] = (m < 90) ? W_out[m] : 0.f;
        } else if (tid < 96) {
            const int l = tid - 92;
            actb[l][90] = 0.f; actb[l][91] = 0.f; infb[l][90] = 0.f; infb[l][91] = 0.f;
            hR[l * 92 + 90] = 0.f; hR[l * 92 + 91] = 0.f;   // rows 0..3 pad (rest below)
        } else if (tid < 108) {
            const int l = tid - 96 + 4;
            hR[l * 92 + 90] = 0.f; hR[l * 92 + 91] = 0.f;   // rows 4..15 pad
        }
    } else if (tid < 224) {
        const int lane = tid & 63;                          // wave 3, lanes 0..31
        const bool valid = (lane < TIL);
        const int kg = k0 + (valid ? lane : 0);
        float nv = 0.f, sv = 0.f;
        bool act = false;
        if (valid) {
            nv = nb_adj[(size_t)q * KU + kg];
            sv = succ_adj[(size_t)q * KU + kg];
            act = (nv != 0.f) || (sv != 0.f) || (kg == q);
            nbvL[lane] = nv; svL[lane] = sv;
        }
        const unsigned long long mb = __ballot(act);
        if (valid) {
            const int rank = (int)__popcll(mb & ((1ull << lane) - 1ull));
            rowslotS[lane] = act ? rank : -1;
            if (act) listS[rank] = lane;
            if (lane == 0) nactS = (int)__popcll(mb);
        }
    } else {
        for (int c = tid - 224; c < 273; c += 32) {
            gi0L[c] = (c < 272) ? ws[OFF_GI0 + c] : 0.f;
            biL[c] = (c < 270) ? bi_rnn[c] : 0.f;
        }
    }
    __syncthreads();   // #1

    // ---------- GEMM: gh = h @ Wh (+bh), Wh streamed from L2, gate triples ----------
    const int rowg = tid >> 5, tc = tid & 31;     // rowg 0..7 -> 2 rows each
    float acc[2][9];
    if (tc < 30) {
        const int m0 = tc * 3;
#pragma unroll
        for (int r = 0; r < 2; ++r)
#pragma unroll
            for (int j = 0; j < 9; ++j) acc[r][j] = 0.f;
        const float* pw0 = ws + OFF_WHB + m0;
        const float* pw1 = pw0 + 90 * 92;
        const float* pw2 = pw1 + 90 * 92;
#pragma unroll 5
        for (int k = 0; k < 90; ++k) {
            const float2 h = *(const float2*)(hT + k * 20 + rowg * 2);
            const f3v w0 = *(const f3v*)(pw0 + k * 92);
            const f3v w1 = *(const f3v*)(pw1 + k * 92);
            const f3v w2 = *(const f3v*)(pw2 + k * 92);
            acc[0][0] += h.x * w0.x; acc[0][1] += h.x * w0.y; acc[0][2] += h.x * w0.z;
            acc[0][3] += h.x * w1.x; acc[0][4] += h.x * w1.y; acc[0][5] += h.x * w1.z;
            acc[0][6] += h.x * w2.x; acc[0][7] += h.x * w2.y; acc[0][8] += h.x * w2.z;
            acc[1][0] += h.y * w0.x; acc[1][1] += h.y * w0.y; acc[1][2] += h.y * w0.z;
            acc[1][3] += h.y * w1.x; acc[1][4] += h.y * w1.y; acc[1][5] += h.y * w1.z;
            acc[1][6] += h.y * w2.x; acc[1][7] += h.y * w2.y; acc[1][8] += h.y * w2.z;
        }
        float bhv[9];
#pragma unroll
        for (int g = 0; g < 3; ++g)
#pragma unroll
            for (int i = 0; i < 3; ++i) bhv[g * 3 + i] = bh_rnn[g * 90 + m0 + i];
#pragma unroll
        for (int r = 0; r < 2; ++r)
#pragma unroll
            for (int j = 0; j < 9; ++j) acc[r][j] += bhv[j];
    }

    // ---------- chains (all 4 waves; typically 0-2 rows active per tile) ----------
    {
        const int w = tid >> 6;
        const int lane = tid & 63;
        const int nact = nactS;
        for (int e = w; e < nact; e += 4) {
            const int r = listS[e];
            const float nv = nbvL[r], sv = svL[r];
            const bool isq = (k0 + r == q);
            for (int m = lane; m < 90; m += 64) {
                float s = 0.f;
                if (nv != 0.f) {
                    const float4* wrow = (const float4*)(ws + OFF_SYLO + (size_t)m * 92);
                    const float4* hr4 = (const float4*)&hR[r * 92];
                    float d = 0.f;
#pragma unroll 4
                    for (int p = 0; p < 23; ++p) d += dot4(hr4[p], wrow[p]);
                    s = nv * fmaxf(nsyL[m] + ws[OFF_CEB + (size_t)(k0 + r) * 90 + m] + d, 0.f);
                }
                if (isq) s += rfL[m];
                actb[w][m] = 0.5f * s + 0.5f * sv * pvL[m];
            }
            WAVE_SYNC();
            for (int m = lane; m < 90; m += 64) {
                const float4* wrow = (const float4*)(ws + OFF_AGG + (size_t)m * 92);
                const float4* av = (const float4*)&actb[w][0];
                float d = baggL[m];
#pragma unroll 4
                for (int p = 0; p < 23; ++p) d += dot4(av[p], wrow[p]);
                infb[w][m] = fmaxf(d, 0.f);
            }
            WAVE_SYNC();
            for (int c = lane; c < 270; c += 64) {
                const float4* wrow = (const float4*)(ws + OFF_WIR + (size_t)c * 92);
                const float4* iv = (const float4*)&infb[w][0];
                float d = biL[c];
#pragma unroll 4
                for (int p = 0; p < 23; ++p) d += dot4(iv[p], wrow[p]);
                giL[e * 273 + c] = d;
            }
            WAVE_SYNC();
        }
    }
    __syncthreads();   // #2 — giL complete

    // ---------- gates in registers ----------
    if (tc < 30) {
        const int m0 = tc * 3;
#pragma unroll
        for (int r = 0; r < 2; ++r) {
            const int row = rowg * 2 + r;
            const int slot = rowslotS[row];
            const float* gs = (slot >= 0) ? &giL[slot * 273] : gi0L;
            float hn[3];
#pragma unroll
            for (int i = 0; i < 3; ++i) {
                const int m = m0 + i;
                const float rg = sigf(gs[m] + acc[r][i]);
                const float zg = sigf(gs[90 + m] + acc[r][3 + i]);
                const float gg = tanhf_(gs[180 + m] + rg * acc[r][6 + i]);
                const float hold = hR[row * 92 + m];
                hn[i] = (1.f - zg) * gg + zg * hold;
            }
            hR[row * 92 + m0] = hn[0];
            hR[row * 92 + m0 + 1] = hn[1];
            hR[row * 92 + m0 + 2] = hn[2];
            f3v o; o.x = hn[0]; o.y = hn[1]; o.z = hn[2];
            *(f3v*)(stOut + ((size_t)(bb * KU + k0 + row)) * 90 + m0) = o;
        }
    }
    __syncthreads();   // #3 — hR = new states

    // ---------- out head: 16 threads/row + shuffle reduce ----------
    {
        const int row = tid >> 4, j = tid & 15;
        const int mstart = j * 6;
        float p = 0.f;
#pragma unroll
        for (int mm = 0; mm < 6; ++mm) {
            const int m = mstart + mm;
            if (m < 90) p += hR[row * 92 + m] * woutL[m];
        }
#pragma unroll
        for (int o = 1; o < 16; o <<= 1) p += __shfl_xor(p, o);
        if (j == 0)
            out[(size_t)t * NB * KU + (size_t)bb * KU + k0 + row] = sigf(p + b_out[0]);
    }
}

extern "C" void kernel_launch(void* const* d_in, const int* in_sizes, int n_in,
                              void* d_out, int out_size, void* d_ws, size_t ws_size,
                              hipStream_t stream) {
    const int* questions = (const int*)d_in[0];
    const int* answers = (const int*)d_in[1];
    const float* response_emb = (const float*)d_in[2];
    const float* concept_emb = (const float*)d_in[3];
    const float* nb_adj = (const float*)d_in[4];
    const float* succ_adj = (const float*)d_in[5];
    const float* Wi_self = (const float*)d_in[6];
    const float* Wh_self = (const float*)d_in[7];
    const float* bi_self = (const float*)d_in[8];
    const float* bh_self = (const float*)d_in[9];
    const float* Wi_rnn = (const float*)d_in[10];
    const float* Wh_rnn = (const float*)d_in[11];
    const float* bi_rnn = (const float*)d_in[12];
    const float* bh_rnn = (const float*)d_in[13];
    const float* W_sync = (const float*)d_in[14];
    const float* b_sync = (const float*)d_in[15];
    const float* W_prop = (const float*)d_in[16];
    const float* b_prop = (const float*)d_in[17];
    const float* W_agg = (const float*)d_in[18];
    const float* b_agg = (const float*)d_in[19];
    const float* W_out = (const float*)d_in[20];
    const float* b_out = (const float*)d_in[21];

    float* out = (float*)d_out;
    float* stFinal = out + (size_t)NT * NB * KU;   // states region of d_out
    float* ws = (float*)d_ws;

    hipMemsetAsync(stFinal, 0, (size_t)NB * KU * 90 * sizeof(float), stream);
    skt_prep<<<177, 256, 0, stream>>>(concept_emb, W_sync, b_sync, W_agg, W_prop, Wi_rnn,
                                      Wh_rnn, Wi_self, Wh_self, bi_rnn, b_agg, ws);
    for (int t = 0; t < NT; ++t) {
        const float* sin = (t & 1) ? ws : stFinal;
        float* sout = (t & 1) ? stFinal : ws;
        skt_batch<<<NB, 320, 0, stream>>>(questions, answers, response_emb, concept_emb,
                                          nb_adj, bi_self, bh_self, b_prop, ws, sin, t);
        skt_tile<<<NB * 32, 256, 0, stream>>>(questions, nb_adj, succ_adj, bi_rnn, bh_rnn,
                                              b_agg, W_out, b_out, ws, sin, sout, out, t);
    }
}

// Round 6
// 4748.048 us; speedup vs baseline: 1.2235x; 1.2235x over previous
//
#include <hip/hip_runtime.h>

#define KU 512
#define NB 32
#define NT 64
#define TIL 16
#define SLOTS 16
#define NBMAX 40

// ---- ws float offsets ----
#define N_PONG   (KU * NB * 90)
#define OFF_SYLO (N_PONG)                      // W_sync[0:90]^T   [90][92]
#define OFF_SYMID (OFF_SYLO + 90 * 92)         // W_sync[90:180]^T [90][92]
#define OFF_AGG  (OFF_SYMID + 90 * 92)         // W_agg^T          [90][92]
#define OFF_WIR  (OFF_AGG + 90 * 92)           // Wi_rnn^T         [270][92]
#define OFF_WPR  (OFF_WIR + 270 * 92)          // W_prop^T         [90][180]
#define OFF_WIS  (OFF_WPR + 90 * 180)          // Wi_self^T        [270][92]
#define OFF_WHS  (OFF_WIS + 270 * 92)          // Wh_self^T        [270][92]
#define OFF_CEB  (OFF_WHS + 270 * 92)          // ce_sync+b_sync   [512][90]
#define OFF_GI0  (OFF_CEB + KU * 90)           // gi0 [272]
#define OFF_ABUF (OFF_GI0 + 272)               // [96][92]
#define OFF_WHT  (OFF_ABUF + 96 * 92)          // ushort [3][96][96] Wh^T bf16
#define OFF_STBF (OFF_WHT + (3 * 96 * 96) / 2) // ushort [16384][96] states bf16

typedef short bf16x8 __attribute__((ext_vector_type(8)));
typedef float f32x4 __attribute__((ext_vector_type(4)));

__device__ __forceinline__ float sigf(float x) { return 1.0f / (1.0f + __expf(-x)); }
__device__ __forceinline__ float tanhf_(float x) {
    float e = __expf(2.0f * x);
    return 1.0f - 2.0f / (e + 1.0f);
}
__device__ __forceinline__ float dot4(float4 a, float4 b) {
    return a.x * b.x + a.y * b.y + a.z * b.z + a.w * b.w;
}
__device__ __forceinline__ unsigned short f2bf(float f) {
    union { float f; unsigned u; } v; v.f = f;
    unsigned r = v.u + 0x7FFFu + ((v.u >> 16) & 1u);
    return (unsigned short)(r >> 16);
}
#define WAVE_SYNC() { asm volatile("s_waitcnt lgkmcnt(0)" ::: "memory"); __builtin_amdgcn_sched_barrier(0); }

// ============ prep: transposed weights + WhT bf16 + ce_sync + gi0 ============
__global__ void skt_prep(const float* __restrict__ concept_emb, const float* __restrict__ W_sync,
                         const float* __restrict__ b_sync, const float* __restrict__ W_agg,
                         const float* __restrict__ W_prop, const float* __restrict__ Wi_rnn,
                         const float* __restrict__ Wh_rnn, const float* __restrict__ Wi_self,
                         const float* __restrict__ Wh_self, const float* __restrict__ bi_rnn,
                         const float* __restrict__ b_agg, float* __restrict__ ws) {
    const int blk = blockIdx.x, tid = threadIdx.x;
    if (blk < 128) {                       // ce_syncB[512][90]
        for (int rr = 0; rr < 4; ++rr) {
            const int k = blk * 4 + rr;
            if (tid < 90) {
                float acc = b_sync[tid];
                for (int kk = 0; kk < 90; ++kk)
                    acc += concept_emb[k * 90 + kk] * W_sync[(180 + kk) * 90 + tid];
                ws[OFF_CEB + k * 90 + tid] = acc;
            }
        }
    } else if (blk < 137) {                // WisT[270][92]
        const int c0 = (blk - 128) * 30;
        for (int rr = 0; rr < 30; ++rr) {
            const int c = c0 + rr;
            if (tid < 92) ws[OFF_WIS + c * 92 + tid] = (tid < 90) ? Wi_self[tid * 270 + c] : 0.f;
        }
    } else if (blk < 146) {                // WhsT[270][92]
        const int c0 = (blk - 137) * 30;
        for (int rr = 0; rr < 30; ++rr) {
            const int c = c0 + rr;
            if (tid < 92) ws[OFF_WHS + c * 92 + tid] = (tid < 90) ? Wh_self[tid * 270 + c] : 0.f;
        }
    } else if (blk < 155) {                // WirT[270][92]
        const int c0 = (blk - 146) * 30;
        for (int rr = 0; rr < 30; ++rr) {
            const int c = c0 + rr;
            if (tid < 92) ws[OFF_WIR + c * 92 + tid] = (tid < 90) ? Wi_rnn[tid * 270 + c] : 0.f;
        }
    } else if (blk < 158) {                // WsyT_lo[90][92]
        const int m0 = (blk - 155) * 30;
        for (int rr = 0; rr < 30; ++rr) {
            const int m = m0 + rr;
            if (tid < 92) ws[OFF_SYLO + m * 92 + tid] = (tid < 90) ? W_sync[tid * 90 + m] : 0.f;
        }
    } else if (blk < 161) {                // WsyT_mid[90][92]
        const int m0 = (blk - 158) * 30;
        for (int rr = 0; rr < 30; ++rr) {
            const int m = m0 + rr;
            if (tid < 92) ws[OFF_SYMID + m * 92 + tid] = (tid < 90) ? W_sync[(90 + tid) * 90 + m] : 0.f;
        }
    } else if (blk < 164) {                // WaggT[90][92]
        const int m0 = (blk - 161) * 30;
        for (int rr = 0; rr < 30; ++rr) {
            const int m = m0 + rr;
            if (tid < 92) ws[OFF_AGG + m * 92 + tid] = (tid < 90) ? W_agg[tid * 90 + m] : 0.f;
        }
    } else if (blk < 167) {                // WprT[90][180]
        const int m0 = (blk - 164) * 30;
        for (int rr = 0; rr < 30; ++rr) {
            const int m = m0 + rr;
            if (tid < 180) ws[OFF_WPR + m * 180 + tid] = W_prop[tid * 90 + m];
        }
    } else if (blk < 170) {                // WhT bf16 [g][96 n][96 k]
        const int g = blk - 167;
        unsigned short* whtp = (unsigned short*)(ws + OFF_WHT);
        for (int idx = tid; idx < 96 * 96; idx += 256) {
            const int n = idx / 96, k = idx - n * 96;
            const float v = (n < 90 && k < 90) ? Wh_rnn[k * 270 + g * 90 + n] : 0.f;
            whtp[g * 9216 + idx] = f2bf(v);
        }
    } else if (blk == 170) {               // gi0[272] = bi_rnn + relu(b_agg)@Wi_rnn
        for (int c = tid; c < 272; c += 256) {
            float acc = 0.f;
            if (c < 270) {
                acc = bi_rnn[c];
                for (int kk = 0; kk < 90; ++kk)
                    acc += fmaxf(b_agg[kk], 0.f) * Wi_rnn[kk * 270 + c];
            }
            ws[OFF_GI0 + c] = acc;
        }
    }
}

// ============ K1: per-batch self GRU, nsync, pvec, reflec ============
__global__ __launch_bounds__(320, 1) void skt_batch(
    const int* __restrict__ qs, const int* __restrict__ as_,
    const float* __restrict__ response_emb, const float* __restrict__ concept_emb,
    const float* __restrict__ nb_adj, const float* __restrict__ bi_self,
    const float* __restrict__ bh_self, const float* __restrict__ b_prop,
    float* __restrict__ ws, const float* __restrict__ stIn, int t) {
    __shared__ alignas(16) float re[92], ssv[92], ceq[92], nsv[92], xprop[184];
    __shared__ alignas(16) float giA[272], ghA[272];
    __shared__ alignas(16) float nsyL[92], pvL[92];
    __shared__ alignas(16) float hnb[NBMAX][92];
    __shared__ alignas(16) float rfp[3][92];
    __shared__ float nbw[NBMAX];
    __shared__ int nblist[NBMAX];
    __shared__ int nnbS;

    const int tid = threadIdx.x;
    const int b = blockIdx.x;
    const int q = qs[b * NT + t], a = as_[b * NT + t];

    if (tid < 90) {
        re[tid] = response_emb[(size_t)a * 90 + tid];
        ssv[tid] = stIn[((size_t)(b * KU + q)) * 90 + tid];
        ceq[tid] = concept_emb[(size_t)q * 90 + tid];
    } else if (tid < 92) { re[tid] = 0.f; ssv[tid] = 0.f; ceq[tid] = 0.f; nsv[tid] = 0.f; }
    if (tid >= 256) {
        const int lane = tid - 256;
        int base = 0;
        for (int ch = 0; ch < 8; ++ch) {
            const int kp = ch * 64 + lane;
            const float nv = nb_adj[(size_t)q * KU + kp];
            const unsigned long long mb = __ballot(nv != 0.f);
            const int idx = base + (int)__popcll(mb & ((1ull << lane) - 1ull));
            if (nv != 0.f && idx < NBMAX) { nblist[idx] = kp; nbw[idx] = nv; }
            base += (int)__popcll(mb);
        }
        if (lane == 0) nnbS = (base < NBMAX) ? base : NBMAX;
    }
    __syncthreads();
    if (tid < 270) {
        float a1 = bi_self[tid], a2 = bh_self[tid];
        const float4* w1 = (const float4*)(ws + OFF_WIS + (size_t)tid * 92);
        const float4* w2 = (const float4*)(ws + OFF_WHS + (size_t)tid * 92);
        const float4* rv = (const float4*)re;
        const float4* sv4 = (const float4*)ssv;
#pragma unroll 4
        for (int p = 0; p < 23; ++p) { a1 += dot4(rv[p], w1[p]); a2 += dot4(sv4[p], w2[p]); }
        giA[tid] = a1; ghA[tid] = a2;
    }
    __syncthreads();
    if (tid < 90) {
        const float r = sigf(giA[tid] + ghA[tid]);
        const float z = sigf(giA[90 + tid] + ghA[90 + tid]);
        const float g = tanhf_(giA[180 + tid] + r * ghA[180 + tid]);
        const float ns = (1.f - z) * g + z * ssv[tid];
        nsv[tid] = ns;
        xprop[tid] = ns - ssv[tid];
        xprop[90 + tid] = ceq[tid];
    } else if (tid >= 92) {
        const int nnb = nnbS;
        const int nnb4 = (nnb + 3) & ~3;
        for (int i = tid - 92; i < nnb4 * 46; i += 228) {
            const int j = i / 46, c2 = i - j * 46;
            float2 v = make_float2(0.f, 0.f);
            if (j < nnb && c2 < 45)
                v = ((const float2*)(stIn + ((size_t)(b * KU + nblist[j])) * 90))[c2];
            ((float2*)&hnb[j][0])[c2] = v;
        }
    }
    __syncthreads();
    if (tid < 90) {
        const float4* wm = (const float4*)(ws + OFF_SYMID + (size_t)tid * 92);
        const float4* nv4 = (const float4*)nsv;
        float d = 0.f;
#pragma unroll 4
        for (int p = 0; p < 23; ++p) d += dot4(nv4[p], wm[p]);
        nsyL[tid] = d;
    } else if (tid < 180) {
        const int m = tid - 90;
        const float4* wp = (const float4*)(ws + OFF_WPR + (size_t)m * 180);
        const float4* xp = (const float4*)xprop;
        float d = b_prop[m];
#pragma unroll 5
        for (int p = 0; p < 45; ++p) d += dot4(xp[p], wp[p]);
        pvL[m] = fmaxf(d, 0.f);
    }
    __syncthreads();
    if (tid < 270) {
        const int g = (tid >= 180) ? 2 : ((tid >= 90) ? 1 : 0);
        const int m = tid - g * 90;
        const int nnb = nnbS;
        const float nsym = nsyL[m];
        const float4* wrow = (const float4*)(ws + OFF_SYLO + (size_t)m * 92);
        float racc = 0.f;
        for (int j = g; j < nnb; j += 3) {
            const float4* hj = (const float4*)&hnb[j][0];
            float d = 0.f;
#pragma unroll 4
            for (int p = 0; p < 23; ++p) d += dot4(hj[p], wrow[p]);
            racc += nbw[j] * fmaxf(nsym + ws[OFF_CEB + (size_t)nblist[j] * 90 + m] + d, 0.f);
        }
        rfp[g][m] = racc;
    }
    __syncthreads();
    if (tid < 90) {
        ws[OFF_ABUF + (size_t)b * 92 + tid] = nsyL[tid];
        ws[OFF_ABUF + (size_t)(32 + b) * 92 + tid] = pvL[tid];
        ws[OFF_ABUF + (size_t)(64 + b) * 92 + tid] = rfp[0][tid] + rfp[1][tid] + rfp[2][tid];
    }
}

// ============ K2: 16-row tile, 384 thr (6 waves = 6 m-tiles), MFMA GEMM ============
__global__ __launch_bounds__(384) void skt_tile(
    const int* __restrict__ qs, const float* __restrict__ nb_adj,
    const float* __restrict__ succ_adj, const float* __restrict__ bi_rnn,
    const float* __restrict__ bh_rnn, const float* __restrict__ b_agg,
    const float* __restrict__ W_out, const float* __restrict__ b_out,
    float* __restrict__ ws, const float* __restrict__ stIn, float* __restrict__ stOut,
    float* __restrict__ out, int t) {
    __shared__ alignas(16) float hR[TIL * 92];
    __shared__ alignas(16) float giL[SLOTS * 273];
    __shared__ alignas(16) float gi0L[273], biL[273], bhL[272];
    __shared__ alignas(16) float nsyL[92], pvL[92], rfL[92], baggL[92], woutL[92];
    __shared__ alignas(16) float actb[6][92], infb[6][92];
    __shared__ float nbvL[TIL], svL[TIL];
    __shared__ int rowslotS[TIL], listS[TIL];
    __shared__ int nactS;

    const int tid = threadIdx.x;
    const int bb = blockIdx.x >> 5;
    const int k0 = (blockIdx.x & 31) * TIL;
    const int q = qs[bb * NT + t];

    // ---------- stage ----------
    if (tid < 192) {
        for (int idx = tid; idx < 46 * TIL; idx += 192) {
            const int row = idx & 15, c2 = idx >> 4;
            float2 v = make_float2(0.f, 0.f);
            if (c2 < 45)
                v = ((const float2*)(stIn + ((size_t)(bb * KU + k0 + row)) * 90))[c2];
            ((float2*)&hR[row * 92])[c2] = v;
        }
    } else if (tid < 256) {
        const int lane = tid & 63;
        const bool valid = (lane < TIL);
        const int kg = k0 + (valid ? lane : 0);
        float nv = 0.f, sv = 0.f;
        bool act = false;
        if (valid) {
            nv = nb_adj[(size_t)q * KU + kg];
            sv = succ_adj[(size_t)q * KU + kg];
            act = (nv != 0.f) || (sv != 0.f) || (kg == q);
            nbvL[lane] = nv; svL[lane] = sv;
        }
        const unsigned long long mb = __ballot(act);
        if (valid) {
            const int rank = (int)__popcll(mb & ((1ull << lane) - 1ull));
            rowslotS[lane] = act ? rank : -1;
            if (act) listS[rank] = lane;
            if (lane == 0) nactS = (int)__popcll(mb);
        }
    } else if (tid < 320) {
        for (int c = tid - 256; c < 273; c += 64) {
            gi0L[c] = (c < 272) ? ws[OFF_GI0 + c] : 0.f;
            biL[c] = (c < 270) ? bi_rnn[c] : 0.f;
            if (c < 272) bhL[c] = (c < 270) ? bh_rnn[c] : 0.f;
        }
    } else {
        const int l = tid - 320;
        for (int m = l; m < 92; m += 64) {
            nsyL[m] = ws[OFF_ABUF + (size_t)bb * 92 + m];
            pvL[m] = ws[OFF_ABUF + (size_t)(32 + bb) * 92 + m];
            rfL[m] = ws[OFF_ABUF + (size_t)(64 + bb) * 92 + m];
            baggL[m] = (m < 90) ? b_agg[m] : 0.f;
            woutL[m] = (m < 90) ? W_out[m] : 0.f;
        }
        if (l < 12) { actb[l >> 1][90 + (l & 1)] = 0.f; infb[l >> 1][90 + (l & 1)] = 0.f; }
    }
    __syncthreads();   // #1

    // ---------- MFMA fragment loads (in flight during chains) ----------
    const int w = tid >> 6;            // wave 0..5 -> m-tile m0=16w
    const int lane = tid & 63;
    const int lr = lane & 15, lh = lane >> 4;
    const int m0 = w * 16;
    unsigned short* stBfp = (unsigned short*)(ws + OFF_STBF);
    const unsigned short* whtp = (const unsigned short*)(ws + OFF_WHT);

    bf16x8 afr[3], bfr[3][3];
    {
        const unsigned short* abase = stBfp + ((size_t)(bb * KU + k0 + lr)) * 96 + 8 * lh;
#pragma unroll
        for (int kk = 0; kk < 3; ++kk) afr[kk] = *(const bf16x8*)(abase + 32 * kk);
#pragma unroll
        for (int g = 0; g < 3; ++g) {
            const unsigned short* bbase = whtp + ((size_t)(g * 96 + m0 + lr)) * 96 + 8 * lh;
#pragma unroll
            for (int kk = 0; kk < 3; ++kk) bfr[g][kk] = *(const bf16x8*)(bbase + 32 * kk);
        }
    }

    // ---------- chains (sparse active rows; all 6 waves, stride 6) ----------
    {
        const int nact = nactS;
        for (int e = w; e < nact; e += 6) {
            const int r = listS[e];
            const float nv = nbvL[r], sv = svL[r];
            const bool isq = (k0 + r == q);
            for (int m = lane; m < 90; m += 64) {
                float s = 0.f;
                if (nv != 0.f) {
                    const float4* wrow = (const float4*)(ws + OFF_SYLO + (size_t)m * 92);
                    const float4* hr4 = (const float4*)&hR[r * 92];
                    float d = 0.f;
#pragma unroll 4
                    for (int p = 0; p < 23; ++p) d += dot4(hr4[p], wrow[p]);
                    s = nv * fmaxf(nsyL[m] + ws[OFF_CEB + (size_t)(k0 + r) * 90 + m] + d, 0.f);
                }
                if (isq) s += rfL[m];
                actb[w][m] = 0.5f * s + 0.5f * sv * pvL[m];
            }
            WAVE_SYNC();
            for (int m = lane; m < 90; m += 64) {
                const float4* wrow = (const float4*)(ws + OFF_AGG + (size_t)m * 92);
                const float4* av = (const float4*)&actb[w][0];
                float d = baggL[m];
#pragma unroll 4
                for (int p = 0; p < 23; ++p) d += dot4(av[p], wrow[p]);
                infb[w][m] = fmaxf(d, 0.f);
            }
            WAVE_SYNC();
            for (int c = lane; c < 270; c += 64) {
                const float4* wrow = (const float4*)(ws + OFF_WIR + (size_t)c * 92);
                const float4* iv = (const float4*)&infb[w][0];
                float d = biL[c];
#pragma unroll 4
                for (int p = 0; p < 23; ++p) d += dot4(iv[p], wrow[p]);
                giL[e * 273 + c] = d;
            }
            WAVE_SYNC();
        }
    }

    // ---------- MFMA: gh[m-tile] for 3 gates ----------
    f32x4 acg[3];
#pragma unroll
    for (int g = 0; g < 3; ++g) acg[g] = f32x4{0.f, 0.f, 0.f, 0.f};
#pragma unroll
    for (int g = 0; g < 3; ++g)
#pragma unroll
        for (int kk = 0; kk < 3; ++kk)
            acg[g] = __builtin_amdgcn_mfma_f32_16x16x32_bf16(afr[kk], bfr[g][kk], acg[g], 0, 0, 0);
    __syncthreads();   // #2 — giL complete

    // ---------- gates in registers (D layout: row=4*lh+r, col=m0+lr) ----------
    const int m = m0 + lr;
    if (m < 90) {
        const float bh_r = bhL[m], bh_z = bhL[90 + m], bh_g = bhL[180 + m];
#pragma unroll
        for (int r = 0; r < 4; ++r) {
            const int row = 4 * lh + r;
            const int slot = rowslotS[row];
            const float* gs = (slot >= 0) ? &giL[slot * 273] : gi0L;
            const float rg = sigf(gs[m] + acg[0][r] + bh_r);
            const float zg = sigf(gs[90 + m] + acg[1][r] + bh_z);
            const float gg = tanhf_(gs[180 + m] + rg * (acg[2][r] + bh_g));
            const float hold = hR[row * 92 + m];
            const float hn = (1.f - zg) * gg + zg * hold;
            hR[row * 92 + m] = hn;
            stOut[((size_t)(bb * KU + k0 + row)) * 90 + m] = hn;
            stBfp[((size_t)(bb * KU + k0 + row)) * 96 + m] = f2bf(hn);
        }
    }
    __syncthreads();   // #3 — hR = new states

    // ---------- out head: 16 threads/row ----------
    if (tid < 256) {
        const int row = tid >> 4, j = tid & 15;
        const int mstart = j * 6;
        float p = 0.f;
#pragma unroll
        for (int mm = 0; mm < 6; ++mm) {
            const int mi = mstart + mm;
            if (mi < 90) p += hR[row * 92 + mi] * woutL[mi];
        }
#pragma unroll
        for (int o = 1; o < 16; o <<= 1) p += __shfl_xor(p, o);
        if (j == 0)
            out[(size_t)t * NB * KU + (size_t)bb * KU + k0 + row] = sigf(p + b_out[0]);
    }
}

extern "C" void kernel_launch(void* const* d_in, const int* in_sizes, int n_in,
                              void* d_out, int out_size, void* d_ws, size_t ws_size,
                              hipStream_t stream) {
    const int* questions = (const int*)d_in[0];
    const int* answers = (const int*)d_in[1];
    const float* response_emb = (const float*)d_in[2];
    const float* concept_emb = (const float*)d_in[3];
    const float* nb_adj = (const float*)d_in[4];
    const float* succ_adj = (const float*)d_in[5];
    const float* Wi_self = (const float*)d_in[6];
    const float* Wh_self = (const float*)d_in[7];
    const float* bi_self = (const float*)d_in[8];
    const float* bh_self = (const float*)d_in[9];
    const float* Wi_rnn = (const float*)d_in[10];
    const float* Wh_rnn = (const float*)d_in[11];
    const float* bi_rnn = (const float*)d_in[12];
    const float* bh_rnn = (const float*)d_in[13];
    const float* W_sync = (const float*)d_in[14];
    const float* b_sync = (const float*)d_in[15];
    const float* W_prop = (const float*)d_in[16];
    const float* b_prop = (const float*)d_in[17];
    const float* W_agg = (const float*)d_in[18];
    const float* b_agg = (const float*)d_in[19];
    const float* W_out = (const float*)d_in[20];
    const float* b_out = (const float*)d_in[21];

    float* out = (float*)d_out;
    float* stFinal = out + (size_t)NT * NB * KU;   // states region of d_out
    float* ws = (float*)d_ws;

    hipMemsetAsync(stFinal, 0, (size_t)NB * KU * 90 * sizeof(float), stream);
    hipMemsetAsync((void*)(ws + OFF_STBF), 0, (size_t)16384 * 96 * 2, stream);   // bf16 states = 0
    skt_prep<<<171, 256, 0, stream>>>(concept_emb, W_sync, b_sync, W_agg, W_prop, Wi_rnn,
                                      Wh_rnn, Wi_self, Wh_self, bi_rnn, b_agg, ws);
    for (int t = 0; t < NT; ++t) {
        const float* sin = (t & 1) ? ws : stFinal;
        float* sout = (t & 1) ? stFinal : ws;
        skt_batch<<<NB, 320, 0, stream>>>(questions, answers, response_emb, concept_emb,
                                          nb_adj, bi_self, bh_self, b_prop, ws, sin, t);
        skt_tile<<<NB * 32, 384, 0, stream>>>(questions, nb_adj, succ_adj, bi_rnn, bh_rnn,
                                              b_agg, W_out, b_out, ws, sin, sout, out, t);
    }
}

// Round 7
// 3682.861 us; speedup vs baseline: 1.5774x; 1.2892x over previous
//
#include <hip/hip_runtime.h>

#define KU 512
#define NB 32
#define NT 64
#define TIL 64
#define SLOTS 20
#define NBMAX 40

// ---- ws float offsets ----
#define N_PONG   (KU * NB * 90)
#define OFF_SYLO (N_PONG)                      // W_sync[0:90]^T   [90][92]
#define OFF_SYMID (OFF_SYLO + 90 * 92)         // W_sync[90:180]^T [90][92]
#define OFF_AGG  (OFF_SYMID + 90 * 92)         // W_agg^T          [90][92]
#define OFF_WIR  (OFF_AGG + 90 * 92)           // Wi_rnn^T         [270][92]
#define OFF_WPR  (OFF_WIR + 270 * 92)          // W_prop^T         [90][180]
#define OFF_WIS  (OFF_WPR + 90 * 180)          // Wi_self^T        [270][92]
#define OFF_WHS  (OFF_WIS + 270 * 92)          // Wh_self^T        [270][92]
#define OFF_CEB  (OFF_WHS + 270 * 92)          // ce_sync+b_sync   [512][90]
#define OFF_GI0  (OFF_CEB + KU * 90)           // gi0 [272]
#define OFF_ABUF (OFF_GI0 + 272)               // (unused; keeps layout)
#define OFF_WHT  (OFF_ABUF + 96 * 92)          // ushort [3][96][96] Wh^T bf16
#define OFF_STBF (OFF_WHT + (3 * 96 * 96) / 2) // ushort [16384][96] states bf16

typedef short bf16x8 __attribute__((ext_vector_type(8)));
typedef float f32x4 __attribute__((ext_vector_type(4)));

__device__ __forceinline__ float sigf(float x) { return 1.0f / (1.0f + __expf(-x)); }
__device__ __forceinline__ float tanhf_(float x) {
    float e = __expf(2.0f * x);
    return 1.0f - 2.0f / (e + 1.0f);
}
__device__ __forceinline__ float dot4(float4 a, float4 b) {
    return a.x * b.x + a.y * b.y + a.z * b.z + a.w * b.w;
}
__device__ __forceinline__ unsigned short f2bf(float f) {
    union { float f; unsigned u; } v; v.f = f;
    unsigned r = v.u + 0x7FFFu + ((v.u >> 16) & 1u);
    return (unsigned short)(r >> 16);
}
#define WAVE_SYNC() { asm volatile("s_waitcnt lgkmcnt(0)" ::: "memory"); __builtin_amdgcn_sched_barrier(0); }

// ============ prep: transposed weights + WhT bf16 + ce_sync + gi0 ============
__global__ void skt_prep(const float* __restrict__ concept_emb, const float* __restrict__ W_sync,
                         const float* __restrict__ b_sync, const float* __restrict__ W_agg,
                         const float* __restrict__ W_prop, const float* __restrict__ Wi_rnn,
                         const float* __restrict__ Wh_rnn, const float* __restrict__ Wi_self,
                         const float* __restrict__ Wh_self, const float* __restrict__ bi_rnn,
                         const float* __restrict__ b_agg, float* __restrict__ ws) {
    const int blk = blockIdx.x, tid = threadIdx.x;
    if (blk < 128) {                       // ce_syncB[512][90]
        for (int rr = 0; rr < 4; ++rr) {
            const int k = blk * 4 + rr;
            if (tid < 90) {
                float acc = b_sync[tid];
                for (int kk = 0; kk < 90; ++kk)
                    acc += concept_emb[k * 90 + kk] * W_sync[(180 + kk) * 90 + tid];
                ws[OFF_CEB + k * 90 + tid] = acc;
            }
        }
    } else if (blk < 137) {                // WisT[270][92]
        const int c0 = (blk - 128) * 30;
        for (int rr = 0; rr < 30; ++rr) {
            const int c = c0 + rr;
            if (tid < 92) ws[OFF_WIS + c * 92 + tid] = (tid < 90) ? Wi_self[tid * 270 + c] : 0.f;
        }
    } else if (blk < 146) {                // WhsT[270][92]
        const int c0 = (blk - 137) * 30;
        for (int rr = 0; rr < 30; ++rr) {
            const int c = c0 + rr;
            if (tid < 92) ws[OFF_WHS + c * 92 + tid] = (tid < 90) ? Wh_self[tid * 270 + c] : 0.f;
        }
    } else if (blk < 155) {                // WirT[270][92]
        const int c0 = (blk - 146) * 30;
        for (int rr = 0; rr < 30; ++rr) {
            const int c = c0 + rr;
            if (tid < 92) ws[OFF_WIR + c * 92 + tid] = (tid < 90) ? Wi_rnn[tid * 270 + c] : 0.f;
        }
    } else if (blk < 158) {                // WsyT_lo[90][92]
        const int m0 = (blk - 155) * 30;
        for (int rr = 0; rr < 30; ++rr) {
            const int m = m0 + rr;
            if (tid < 92) ws[OFF_SYLO + m * 92 + tid] = (tid < 90) ? W_sync[tid * 90 + m] : 0.f;
        }
    } else if (blk < 161) {                // WsyT_mid[90][92]
        const int m0 = (blk - 158) * 30;
        for (int rr = 0; rr < 30; ++rr) {
            const int m = m0 + rr;
            if (tid < 92) ws[OFF_SYMID + m * 92 + tid] = (tid < 90) ? W_sync[(90 + tid) * 90 + m] : 0.f;
        }
    } else if (blk < 164) {                // WaggT[90][92]
        const int m0 = (blk - 161) * 30;
        for (int rr = 0; rr < 30; ++rr) {
            const int m = m0 + rr;
            if (tid < 92) ws[OFF_AGG + m * 92 + tid] = (tid < 90) ? W_agg[tid * 90 + m] : 0.f;
        }
    } else if (blk < 167) {                // WprT[90][180]
        const int m0 = (blk - 164) * 30;
        for (int rr = 0; rr < 30; ++rr) {
            const int m = m0 + rr;
            if (tid < 180) ws[OFF_WPR + m * 180 + tid] = W_prop[tid * 90 + m];
        }
    } else if (blk < 170) {                // WhT bf16 [g][96 n][96 k]
        const int g = blk - 167;
        unsigned short* whtp = (unsigned short*)(ws + OFF_WHT);
        for (int idx = tid; idx < 96 * 96; idx += 256) {
            const int n = idx / 96, k = idx - n * 96;
            const float v = (n < 90 && k < 90) ? Wh_rnn[k * 270 + g * 90 + n] : 0.f;
            whtp[g * 9216 + idx] = f2bf(v);
        }
    } else if (blk == 170) {               // gi0[272] = bi_rnn + relu(b_agg)@Wi_rnn
        for (int c = tid; c < 272; c += 256) {
            float acc = 0.f;
            if (c < 270) {
                acc = bi_rnn[c];
                for (int kk = 0; kk < 90; ++kk)
                    acc += fmaxf(b_agg[kk], 0.f) * Wi_rnn[kk * 270 + c];
            }
            ws[OFF_GI0 + c] = acc;
        }
    }
}

// ============ merged per-step kernel: 256 blocks x 512 thr, TIL=64 ============
__global__ __launch_bounds__(512, 2) void skt_step(
    const int* __restrict__ qs, const int* __restrict__ as_,
    const float* __restrict__ response_emb, const float* __restrict__ concept_emb,
    const float* __restrict__ nb_adj, const float* __restrict__ succ_adj,
    const float* __restrict__ bi_self, const float* __restrict__ bh_self,
    const float* __restrict__ b_prop, const float* __restrict__ bi_rnn,
    const float* __restrict__ bh_rnn, const float* __restrict__ b_agg,
    const float* __restrict__ W_out, const float* __restrict__ b_out,
    float* __restrict__ ws, const float* __restrict__ stIn, float* __restrict__ stOut,
    float* __restrict__ out, int t) {
    __shared__ alignas(16) float hR[TIL * 92];
    __shared__ alignas(16) float giL[SLOTS * 273];
    __shared__ alignas(16) float hnb[NBMAX][92];
    __shared__ alignas(16) float rfd[NBMAX][92];
    __shared__ alignas(16) float giA[272], ghA[272];
    __shared__ alignas(16) float gi0L[273], biL[273], bhL[272];
    __shared__ alignas(16) float re[92], ssv[92], ceq[92], nsv[92], xprop[184];
    __shared__ alignas(16) float nsyL[92], pvL[92], rfL[92], baggL[92], woutL[92];
    __shared__ alignas(16) float actb[8][92], infb[8][92];
    __shared__ float nbw[NBMAX];
    __shared__ int nblist[NBMAX];
    __shared__ float nbvL[TIL], svL[TIL];
    __shared__ int rowslotS[TIL], listS[TIL];
    __shared__ int nactS, nnbS;

    const int tid = threadIdx.x;
    const int bb = blockIdx.x >> 3;
    const int k0 = (blockIdx.x & 7) * TIL;
    const int q = qs[bb * NT + t];
    const int a = as_[bb * NT + t];

    const int w8 = tid >> 6, lane = tid & 63;
    const int lr = lane & 15, lh = lane >> 4;
    const int rt = w8 & 3, cg = w8 >> 2;     // rowtile 0..3, col half 0..1

    unsigned short* stBfp = (unsigned short*)(ws + OFF_STBF);
    const unsigned short* whtp = (const unsigned short*)(ws + OFF_WHT);

    // ---- A-fragments (prev-step bf16 states, own rows) issued immediately ----
    bf16x8 afr[3];
    {
        const unsigned short* abase =
            stBfp + ((size_t)(bb * KU + k0 + rt * 16 + lr)) * 96 + 8 * lh;
#pragma unroll
        for (int kk = 0; kk < 3; ++kk) afr[kk] = *(const bf16x8*)(abase + 32 * kk);
    }

    // ================= B0: stage =================
    if (tid < 360) {                 // hR: 64 rows x 45 float2
        for (int idx = tid; idx < 2880; idx += 360) {
            const int row = idx / 45, c2 = idx - row * 45;
            const float2 v = ((const float2*)(stIn + ((size_t)(bb * KU + k0 + row)) * 90))[c2];
            ((float2*)&hR[row * 92])[c2] = v;
        }
    } else if (tid < 384) {          // hR pads
        for (int i = tid - 360; i < TIL; i += 24) { hR[i * 92 + 90] = 0.f; hR[i * 92 + 91] = 0.f; }
    } else if (tid < 448) {          // wave 6: active-row scan (own 64 rows)
        const int l = tid - 384;
        const int kg = k0 + l;
        const float nv = nb_adj[(size_t)q * KU + kg];
        const float sv = succ_adj[(size_t)q * KU + kg];
        nbvL[l] = nv; svL[l] = sv;
        const bool act = (nv != 0.f) || (sv != 0.f) || (kg == q);
        const unsigned long long mb = __ballot(act);
        const int rank = (int)__popcll(mb & ((1ull << l) - 1ull));
        rowslotS[l] = act ? rank : -1;
        if (act) listS[rank] = l;
        if (l == 0) nactS = (int)__popcll(mb);
    } else {                         // wave 7: neighbor scan of q
        const int l = tid - 448;
        int base = 0;
        for (int ch = 0; ch < 8; ++ch) {
            const int kp = ch * 64 + l;
            const float nv = nb_adj[(size_t)q * KU + kp];
            const unsigned long long mb = __ballot(nv != 0.f);
            const int idx = base + (int)__popcll(mb & ((1ull << l) - 1ull));
            if (nv != 0.f && idx < NBMAX) { nblist[idx] = kp; nbw[idx] = nv; }
            base += (int)__popcll(mb);
        }
        if (l == 0) nnbS = (base < NBMAX) ? base : NBMAX;
    }
    for (int j = tid; j < 270; j += 512) {
        if (j < 90) re[j] = response_emb[(size_t)a * 90 + j];
        else if (j < 180) ssv[j - 90] = stIn[((size_t)(bb * KU + q)) * 90 + (j - 90)];
        else ceq[j - 180] = concept_emb[(size_t)q * 90 + (j - 180)];
    }
    for (int c = tid; c < 273; c += 512) {
        gi0L[c] = (c < 272) ? ws[OFF_GI0 + c] : 0.f;
        biL[c] = (c < 270) ? bi_rnn[c] : 0.f;
        if (c < 272) bhL[c] = (c < 270) ? bh_rnn[c] : 0.f;
    }
    for (int m = tid; m < 92; m += 512) {
        baggL[m] = (m < 90) ? b_agg[m] : 0.f;
        woutL[m] = (m < 90) ? W_out[m] : 0.f;
        if (m >= 90) {
            re[m] = 0.f; ssv[m] = 0.f; ceq[m] = 0.f; nsv[m] = 0.f; rfL[m] = 0.f;
#pragma unroll
            for (int w = 0; w < 8; ++w) { actb[w][m] = 0.f; infb[w][m] = 0.f; }
        }
    }
    if (tid < 4) xprop[180 + tid] = 0.f;
    __syncthreads();   // #B0

    // ================= B1: self-GRU matvecs + neighbor-state staging =================
    for (int j = tid; j < 540; j += 512) {
        if (j < 270) {
            float acc = bi_self[j];
            const float4* w1 = (const float4*)(ws + OFF_WIS + (size_t)j * 92);
            const float4* rv = (const float4*)re;
#pragma unroll 4
            for (int p = 0; p < 23; ++p) acc += dot4(rv[p], w1[p]);
            giA[j] = acc;
        } else {
            const int c = j - 270;
            float acc = bh_self[c];
            const float4* w2 = (const float4*)(ws + OFF_WHS + (size_t)c * 92);
            const float4* sv4 = (const float4*)ssv;
#pragma unroll 4
            for (int p = 0; p < 23; ++p) acc += dot4(sv4[p], w2[p]);
            ghA[c] = acc;
        }
    }
    {
        const int nnb = nnbS;
        const int nnb4 = (nnb + 3) & ~3;
        for (int i = tid; i < nnb4 * 46; i += 512) {
            const int j = i / 46, c2 = i - j * 46;
            float2 v = make_float2(0.f, 0.f);
            if (j < nnb && c2 < 45)
                v = ((const float2*)(stIn + ((size_t)(bb * KU + nblist[j])) * 90))[c2];
            ((float2*)&hnb[j][0])[c2] = v;
        }
    }
    __syncthreads();   // #B1

    // ================= B2: next_self + reflec dots (nsym-independent part) =================
    if (tid < 90) {
        const float r = sigf(giA[tid] + ghA[tid]);
        const float z = sigf(giA[90 + tid] + ghA[90 + tid]);
        const float g = tanhf_(giA[180 + tid] + r * ghA[180 + tid]);
        const float ns = (1.f - z) * g + z * ssv[tid];
        nsv[tid] = ns;
        xprop[tid] = ns - ssv[tid];
        xprop[90 + tid] = ceq[tid];
    }
    {
        const int nnb = nnbS;
        for (int idx = tid; idx < nnb * 90; idx += 512) {
            const int j = idx / 90, m = idx - j * 90;
            float d = ws[OFF_CEB + (size_t)nblist[j] * 90 + m];
            const float4* wrow = (const float4*)(ws + OFF_SYLO + (size_t)m * 92);
            const float4* hj = (const float4*)&hnb[j][0];
#pragma unroll 4
            for (int p = 0; p < 23; ++p) d += dot4(hj[p], wrow[p]);
            rfd[j][m] = d;
        }
    }
    __syncthreads();   // #B2

    // ================= B3: nsync + pvec =================
    if (tid < 90) {
        const float4* wm = (const float4*)(ws + OFF_SYMID + (size_t)tid * 92);
        const float4* nv4 = (const float4*)nsv;
        float d = 0.f;
#pragma unroll 4
        for (int p = 0; p < 23; ++p) d += dot4(nv4[p], wm[p]);
        nsyL[tid] = d;
    } else if (tid < 180) {
        const int m = tid - 90;
        const float4* wp = (const float4*)(ws + OFF_WPR + (size_t)m * 180);
        const float4* xp = (const float4*)xprop;
        float d = b_prop[m];
#pragma unroll 5
        for (int p = 0; p < 45; ++p) d += dot4(xp[p], wp[p]);
        pvL[m] = fmaxf(d, 0.f);
    }
    __syncthreads();   // #B3

    // ================= B4: reflec finish (LDS-only) + MFMA =================
    if (tid < 90) {
        const int nnb = nnbS;
        const float nsym = nsyL[tid];
        float racc = 0.f;
        for (int j = 0; j < nnb; ++j) racc += nbw[j] * fmaxf(nsym + rfd[j][tid], 0.f);
        rfL[tid] = racc;
    }
    f32x4 acc[3][3];
#pragma unroll
    for (int g = 0; g < 3; ++g)
#pragma unroll
        for (int ct = 0; ct < 3; ++ct) acc[g][ct] = f32x4{0.f, 0.f, 0.f, 0.f};
#pragma unroll
    for (int g = 0; g < 3; ++g) {
#pragma unroll
        for (int ct = 0; ct < 3; ++ct) {
            const unsigned short* bbase =
                whtp + ((size_t)(g * 96 + cg * 48 + ct * 16 + lr)) * 96 + 8 * lh;
            const bf16x8 b0 = *(const bf16x8*)(bbase);
            const bf16x8 b1 = *(const bf16x8*)(bbase + 32);
            const bf16x8 b2 = *(const bf16x8*)(bbase + 64);
            acc[g][ct] = __builtin_amdgcn_mfma_f32_16x16x32_bf16(afr[0], b0, acc[g][ct], 0, 0, 0);
            acc[g][ct] = __builtin_amdgcn_mfma_f32_16x16x32_bf16(afr[1], b1, acc[g][ct], 0, 0, 0);
            acc[g][ct] = __builtin_amdgcn_mfma_f32_16x16x32_bf16(afr[2], b2, acc[g][ct], 0, 0, 0);
        }
    }
    __syncthreads();   // #B4

    // ================= B5: chains + gates (multi-pass, SLOTS per pass) =================
    const int nact = nactS;
    const int npass = (nact > 0) ? ((nact + SLOTS - 1) / SLOTS) : 1;
    for (int pass = 0; pass < npass; ++pass) {
        const int e0p = pass * SLOTS;
        int e1p = e0p + SLOTS; if (e1p > nact) e1p = nact;
        for (int e = e0p + w8; e < e1p; e += 8) {
            const int r = listS[e];
            const int slot = e - e0p;
            const float nv = nbvL[r], sv = svL[r];
            const bool isq = (k0 + r == q);
            for (int m = lane; m < 90; m += 64) {
                float s = 0.f;
                if (nv != 0.f) {
                    const float4* wrow = (const float4*)(ws + OFF_SYLO + (size_t)m * 92);
                    const float4* hr4 = (const float4*)&hR[r * 92];
                    float d = 0.f;
#pragma unroll 4
                    for (int p = 0; p < 23; ++p) d += dot4(hr4[p], wrow[p]);
                    s = nv * fmaxf(nsyL[m] + ws[OFF_CEB + (size_t)(k0 + r) * 90 + m] + d, 0.f);
                }
                if (isq) s += rfL[m];
                actb[w8][m] = 0.5f * s + 0.5f * sv * pvL[m];
            }
            WAVE_SYNC();
            for (int m = lane; m < 90; m += 64) {
                const float4* wrow = (const float4*)(ws + OFF_AGG + (size_t)m * 92);
                const float4* av = (const float4*)&actb[w8][0];
                float d = baggL[m];
#pragma unroll 4
                for (int p = 0; p < 23; ++p) d += dot4(av[p], wrow[p]);
                infb[w8][m] = fmaxf(d, 0.f);
            }
            WAVE_SYNC();
            for (int c = lane; c < 270; c += 64) {
                const float4* wrow = (const float4*)(ws + OFF_WIR + (size_t)c * 92);
                const float4* iv = (const float4*)&infb[w8][0];
                float d = biL[c];
#pragma unroll 4
                for (int p = 0; p < 23; ++p) d += dot4(iv[p], wrow[p]);
                giL[slot * 273 + c] = d;
            }
            WAVE_SYNC();
        }
        __syncthreads();   // chains of this pass done

        // gates for rows of this pass (in registers)
#pragma unroll
        for (int ct = 0; ct < 3; ++ct) {
            const int m = cg * 48 + ct * 16 + lr;
            if (m < 90) {
                const float bhr = bhL[m], bhz = bhL[90 + m], bhg = bhL[180 + m];
#pragma unroll
                for (int r4 = 0; r4 < 4; ++r4) {
                    const int row = rt * 16 + 4 * lh + r4;
                    const int sraw = rowslotS[row];
                    const bool mine = (sraw < 0) ? (pass == 0) : (sraw >= e0p && sraw < e1p);
                    if (!mine) continue;
                    const float* gs = (sraw < 0) ? gi0L : &giL[(sraw - e0p) * 273];
                    const float rg = sigf(gs[m] + acc[0][ct][r4] + bhr);
                    const float zg = sigf(gs[90 + m] + acc[1][ct][r4] + bhz);
                    const float gg = tanhf_(gs[180 + m] + rg * (acc[2][ct][r4] + bhg));
                    const float hold = hR[row * 92 + m];
                    const float hn = (1.f - zg) * gg + zg * hold;
                    hR[row * 92 + m] = hn;
                    stOut[((size_t)(bb * KU + k0 + row)) * 90 + m] = hn;
                    stBfp[((size_t)(bb * KU + k0 + row)) * 96 + m] = f2bf(hn);
                }
            }
        }
        __syncthreads();   // gates done (giL reusable; hR stable)
    }

    // ================= B6: out head (8 threads/row) =================
    {
        const int row = tid >> 3, j = tid & 7;
        const int m0 = j * 12;
        float p = 0.f;
#pragma unroll
        for (int mm = 0; mm < 12; ++mm) {
            const int m = m0 + mm;
            if (m < 90) p += hR[row * 92 + m] * woutL[m];
        }
#pragma unroll
        for (int o = 1; o < 8; o <<= 1) p += __shfl_xor(p, o);
        if (j == 0)
            out[(size_t)t * NB * KU + (size_t)bb * KU + k0 + row] = sigf(p + b_out[0]);
    }
}

extern "C" void kernel_launch(void* const* d_in, const int* in_sizes, int n_in,
                              void* d_out, int out_size, void* d_ws, size_t ws_size,
                              hipStream_t stream) {
    const int* questions = (const int*)d_in[0];
    const int* answers = (const int*)d_in[1];
    const float* response_emb = (const float*)d_in[2];
    const float* concept_emb = (const float*)d_in[3];
    const float* nb_adj = (const float*)d_in[4];
    const float* succ_adj = (const float*)d_in[5];
    const float* Wi_self = (const float*)d_in[6];
    const float* Wh_self = (const float*)d_in[7];
    const float* bi_self = (const float*)d_in[8];
    const float* bh_self = (const float*)d_in[9];
    const float* Wi_rnn = (const float*)d_in[10];
    const float* Wh_rnn = (const float*)d_in[11];
    const float* bi_rnn = (const float*)d_in[12];
    const float* bh_rnn = (const float*)d_in[13];
    const float* W_sync = (const float*)d_in[14];
    const float* b_sync = (const float*)d_in[15];
    const float* W_prop = (const float*)d_in[16];
    const float* b_prop = (const float*)d_in[17];
    const float* W_agg = (const float*)d_in[18];
    const float* b_agg = (const float*)d_in[19];
    const float* W_out = (const float*)d_in[20];
    const float* b_out = (const float*)d_in[21];

    float* out = (float*)d_out;
    float* stFinal = out + (size_t)NT * NB * KU;   // states region of d_out
    float* ws = (float*)d_ws;

    hipMemsetAsync(stFinal, 0, (size_t)NB * KU * 90 * sizeof(float), stream);
    hipMemsetAsync((void*)(ws + OFF_STBF), 0, (size_t)16384 * 96 * 2, stream);   // bf16 states = 0
    skt_prep<<<171, 256, 0, stream>>>(concept_emb, W_sync, b_sync, W_agg, W_prop, Wi_rnn,
                                      Wh_rnn, Wi_self, Wh_self, bi_rnn, b_agg, ws);
    for (int t = 0; t < NT; ++t) {
        const float* sin = (t & 1) ? ws : stFinal;
        float* sout = (t & 1) ? stFinal : ws;
        skt_step<<<NB * 8, 512, 0, stream>>>(
            questions, answers, response_emb, concept_emb, nb_adj, succ_adj,
            bi_self, bh_self, b_prop, bi_rnn, bh_rnn, b_agg, W_out, b_out,
            ws, sin, sout, out, t);
    }
}

// Round 8
// 3351.614 us; speedup vs baseline: 1.7333x; 1.0988x over previous
//
#include <hip/hip_runtime.h>

#define KU 512
#define NB 32
#define NT 64
#define TIL 64
#define SLOTS 8
#define NBMAX 40

// ---- ws float offsets ----
#define N_PONG   (KU * NB * 90)
#define OFF_CEB  (N_PONG)                  // ce_sync+b_sync [512][90]
#define OFF_GI0  (OFF_CEB + KU * 90)       // gi0 [272]
#define OFF_WHTF (OFF_GI0 + 288)           // ushort[3][6][3][64][8] Wh B-fragments (27648 ushort)

typedef short bf16x8 __attribute__((ext_vector_type(8)));
typedef float f32x4 __attribute__((ext_vector_type(4)));

__device__ __forceinline__ float sigf(float x) { return 1.0f / (1.0f + __expf(-x)); }
__device__ __forceinline__ float tanhf_(float x) {
    float e = __expf(2.0f * x);
    return 1.0f - 2.0f / (e + 1.0f);
}
__device__ __forceinline__ unsigned short f2bf(float f) {
    union { float f; unsigned u; } v; v.f = f;
    unsigned r = v.u + 0x7FFFu + ((v.u >> 16) & 1u);
    return (unsigned short)(r >> 16);
}

// ============ prep: ce_sync + gi0 + Wh B-fragment layout (once) ============
__global__ void skt_prep(const float* __restrict__ concept_emb, const float* __restrict__ W_sync,
                         const float* __restrict__ b_sync, const float* __restrict__ Wi_rnn,
                         const float* __restrict__ Wh_rnn, const float* __restrict__ bi_rnn,
                         const float* __restrict__ b_agg, float* __restrict__ ws) {
    const int blk = blockIdx.x, tid = threadIdx.x;
    if (blk < 128) {                       // ceb[512][90] = b_sync + ce @ W_sync[180:270]
        for (int rr = 0; rr < 4; ++rr) {
            const int k = blk * 4 + rr;
            if (tid < 90) {
                float acc = b_sync[tid];
                for (int kk = 0; kk < 90; ++kk)
                    acc += concept_emb[k * 90 + kk] * W_sync[(180 + kk) * 90 + tid];
                ws[OFF_CEB + k * 90 + tid] = acc;
            }
        }
    } else if (blk < 131) {                // whtF[g][nb][kk][lane][i] bf16 B-fragments
        const int g = blk - 128;
        unsigned short* p = (unsigned short*)(ws + OFF_WHTF);
        for (int idx = tid; idx < 6 * 3 * 64 * 8; idx += 256) {
            const int i = idx & 7, lane = (idx >> 3) & 63;
            const int rest = idx >> 9;            // nb*3 + kk
            const int kk = rest % 3, nb = rest / 3;
            const int n = nb * 16 + (lane & 15);
            const int k = kk * 32 + (lane >> 4) * 8 + i;
            const float v = (n < 90 && k < 90) ? Wh_rnn[k * 270 + g * 90 + n] : 0.f;
            p[(size_t)g * 9216 + idx] = f2bf(v);
        }
    } else {                               // gi0[272] = bi_rnn + relu(b_agg) @ Wi_rnn
        for (int c = tid; c < 272; c += 256) {
            float acc = 0.f;
            if (c < 270) {
                acc = bi_rnn[c];
                for (int kk = 0; kk < 90; ++kk)
                    acc += fmaxf(b_agg[kk], 0.f) * Wi_rnn[kk * 270 + c];
            }
            ws[OFF_GI0 + c] = acc;
        }
    }
}

// ============ merged per-step kernel: 256 blocks x 512 thr, TIL=64 ============
__global__ __launch_bounds__(512, 1) void skt_step(
    const int* __restrict__ qs, const int* __restrict__ as_,
    const float* __restrict__ response_emb, const float* __restrict__ concept_emb,
    const float* __restrict__ nb_adj, const float* __restrict__ succ_adj,
    const float* __restrict__ Wi_self, const float* __restrict__ Wh_self,
    const float* __restrict__ bi_self, const float* __restrict__ bh_self,
    const float* __restrict__ Wi_rnn, const float* __restrict__ bi_rnn,
    const float* __restrict__ bh_rnn, const float* __restrict__ b_agg,
    const float* __restrict__ W_sync, const float* __restrict__ W_prop,
    const float* __restrict__ b_prop, const float* __restrict__ W_agg,
    const float* __restrict__ W_out, const float* __restrict__ b_out,
    float* __restrict__ ws, const float* __restrict__ stIn, float* __restrict__ stOut,
    float* __restrict__ out, int t) {
    __shared__ alignas(16) float hR[TIL * 100];          // states, stride 100 (bank skew)
    __shared__ alignas(16) float rfd[NBMAX][92];
    __shared__ alignas(16) float giL[SLOTS * 273];
    __shared__ alignas(16) float giA[272], ghA[272];
    __shared__ alignas(16) float gi0L[273], biL[273], bhL[272];
    __shared__ alignas(16) float re[92], ssv[92], ceq[92], nsv[92], xprop[184];
    __shared__ alignas(16) float nsyL[92], pvL[92], baggL[92], woutL[92];
    __shared__ alignas(16) float actb[SLOTS][92], infb[SLOTS][92];
    __shared__ float nbw[NBMAX];
    __shared__ int nblist[NBMAX];
    __shared__ float nbvL[TIL], svL[TIL];
    __shared__ int rowslotS[TIL], listS[TIL];
    __shared__ int nactS, nnbS;

    const int tid = threadIdx.x;
    const int bb = blockIdx.x >> 3;
    const int k0 = (blockIdx.x & 7) * TIL;
    const int q = qs[bb * NT + t];
    const int a = as_[bb * NT + t];
    const bool owner = (q >= k0 && q < k0 + TIL);

    const int w8 = tid >> 6, lane = tid & 63;
    const int lr = lane & 15, lh = lane >> 4;
    const int rt = w8 & 3, cg = w8 >> 2;

    // ================= B0: stage =================
    if (tid < 384) {                     // hR: 64 rows x 50 float2 (cols 90..99 zero)
        for (int idx = tid; idx < TIL * 50; idx += 384) {
            const int row = idx / 50, c2 = idx - row * 50;
            float2 v = make_float2(0.f, 0.f);
            if (c2 < 45)
                v = ((const float2*)(stIn + ((size_t)(bb * KU + k0 + row)) * 90))[c2];
            *(float2*)&hR[row * 100 + 2 * c2] = v;
        }
    } else if (tid < 448) {              // wave 6: active-row scan
        const int l = tid - 384;
        const int kg = k0 + l;
        const float nv = nb_adj[(size_t)q * KU + kg];
        const float sv = succ_adj[(size_t)q * KU + kg];
        nbvL[l] = nv; svL[l] = sv;
        const bool act = (nv != 0.f) || (sv != 0.f) || (kg == q);
        const unsigned long long mb = __ballot(act);
        const int rank = (int)__popcll(mb & ((1ull << l) - 1ull));
        rowslotS[l] = act ? rank : -1;
        if (act) listS[rank] = l;
        if (l == 0) nactS = (int)__popcll(mb);
    } else {                             // wave 7: neighbor scan of q
        const int l = tid - 448;
        int base = 0;
        for (int ch = 0; ch < 8; ++ch) {
            const int kp = ch * 64 + l;
            const float nv = nb_adj[(size_t)q * KU + kp];
            const unsigned long long mb = __ballot(nv != 0.f);
            const int idx = base + (int)__popcll(mb & ((1ull << l) - 1ull));
            if (nv != 0.f && idx < NBMAX) { nblist[idx] = kp; nbw[idx] = nv; }
            base += (int)__popcll(mb);
        }
        if (l == 0) nnbS = (base < NBMAX) ? base : NBMAX;
    }
    for (int j = tid; j < 270; j += 512) {
        if (j < 90) re[j] = response_emb[(size_t)a * 90 + j];
        else if (j < 180) ssv[j - 90] = stIn[((size_t)(bb * KU + q)) * 90 + (j - 90)];
        else ceq[j - 180] = concept_emb[(size_t)q * 90 + (j - 180)];
    }
    for (int c = tid; c < 273; c += 512) {
        gi0L[c] = (c < 272) ? ws[OFF_GI0 + c] : 0.f;
        biL[c] = (c < 270) ? bi_rnn[c] : 0.f;
        if (c < 272) bhL[c] = (c < 270) ? bh_rnn[c] : 0.f;
    }
    for (int m = tid; m < 92; m += 512) {
        baggL[m] = (m < 90) ? b_agg[m] : 0.f;
        woutL[m] = (m < 90) ? W_out[m] : 0.f;
    }
    __syncthreads();   // #B0

    // ================= B1: self-GRU matvecs (k-major, coalesced) + owner rfd + MFMA ====
    for (int c = tid; c < 540; c += 512) {
        if (c < 270) {
            float acc = bi_self[c];
#pragma unroll 6
            for (int k = 0; k < 90; ++k) acc += re[k] * Wi_self[k * 270 + c];
            giA[c] = acc;
        } else {
            const int c2 = c - 270;
            float acc = bh_self[c2];
#pragma unroll 6
            for (int k = 0; k < 90; ++k) acc += ssv[k] * Wh_self[k * 270 + c2];
            ghA[c2] = acc;
        }
    }
    if (owner) {
        const int nnb = nnbS;
        for (int idx = tid; idx < nnb * 90; idx += 512) {
            const int j = idx / 90, m = idx - j * 90;
            const float* xr = stIn + ((size_t)(bb * KU + nblist[j])) * 90;
            float d = ws[OFF_CEB + (size_t)nblist[j] * 90 + m];
#pragma unroll 6
            for (int k = 0; k < 90; ++k) d += xr[k] * W_sync[k * 90 + m];
            rfd[j][m] = d;
        }
    }
    // MFMA: A-frags from hR (f32->bf16), B-frags from pre-swizzled whtF (coalesced)
    f32x4 acc[3][3];
#pragma unroll
    for (int g = 0; g < 3; ++g)
#pragma unroll
        for (int ct = 0; ct < 3; ++ct) acc[g][ct] = f32x4{0.f, 0.f, 0.f, 0.f};
    {
        bf16x8 afr[3];
        const float* ar = &hR[(rt * 16 + lr) * 100];
#pragma unroll
        for (int kk = 0; kk < 3; ++kk) {
            const float4 a0 = *(const float4*)(ar + kk * 32 + lh * 8);
            const float4 a1 = *(const float4*)(ar + kk * 32 + lh * 8 + 4);
            union { bf16x8 v; unsigned short u[8]; } fr;
            fr.u[0] = f2bf(a0.x); fr.u[1] = f2bf(a0.y); fr.u[2] = f2bf(a0.z); fr.u[3] = f2bf(a0.w);
            fr.u[4] = f2bf(a1.x); fr.u[5] = f2bf(a1.y); fr.u[6] = f2bf(a1.z); fr.u[7] = f2bf(a1.w);
            afr[kk] = fr.v;
        }
        const unsigned short* whtF = (const unsigned short*)(ws + OFF_WHTF);
#pragma unroll
        for (int g = 0; g < 3; ++g) {
#pragma unroll
            for (int ct = 0; ct < 3; ++ct) {
                const int nb = cg * 3 + ct;
                const unsigned short* bp = whtF + (size_t)(g * 6 + nb) * 1536 + lane * 8;
                acc[g][ct] = __builtin_amdgcn_mfma_f32_16x16x32_bf16(
                    afr[0], *(const bf16x8*)(bp), acc[g][ct], 0, 0, 0);
                acc[g][ct] = __builtin_amdgcn_mfma_f32_16x16x32_bf16(
                    afr[1], *(const bf16x8*)(bp + 512), acc[g][ct], 0, 0, 0);
                acc[g][ct] = __builtin_amdgcn_mfma_f32_16x16x32_bf16(
                    afr[2], *(const bf16x8*)(bp + 1024), acc[g][ct], 0, 0, 0);
            }
        }
    }
    __syncthreads();   // #B1

    // ================= B2: next_self gates =================
    if (tid < 90) {
        const float r = sigf(giA[tid] + ghA[tid]);
        const float z = sigf(giA[90 + tid] + ghA[90 + tid]);
        const float g = tanhf_(giA[180 + tid] + r * ghA[180 + tid]);
        const float ns = (1.f - z) * g + z * ssv[tid];
        nsv[tid] = ns;
        xprop[tid] = ns - ssv[tid];
        xprop[90 + tid] = ceq[tid];
    }
    __syncthreads();   // #B2

    // ================= B3: nsync + pvec (k-major, coalesced) =================
    if (tid < 90) {
        float d = 0.f;
#pragma unroll 6
        for (int k = 0; k < 90; ++k) d += nsv[k] * W_sync[(90 + k) * 90 + tid];
        nsyL[tid] = d;
    } else if (tid < 180) {
        const int m = tid - 90;
        float d = b_prop[m];
#pragma unroll 6
        for (int k = 0; k < 180; ++k) d += xprop[k] * W_prop[k * 90 + m];
        pvL[m] = fmaxf(d, 0.f);
    }
    __syncthreads();   // #B3

    // ================= C: chains (block-stage-parallel) + gates =================
    const int nact = nactS;
    const int npass = (nact + SLOTS - 1) / SLOTS;
    const int nploop = (npass > 0) ? npass : 1;
    for (int pass = 0; pass < nploop; ++pass) {
        const int e0p = pass * SLOTS;
        int e1p = e0p + SLOTS; if (e1p > nact) e1p = nact;
        const int na = e1p - e0p;

        // C1: act (slot,m)-parallel
        for (int idx = tid; idx < na * 90; idx += 512) {
            const int slot = idx / 90, m = idx - slot * 90;
            const int r = listS[e0p + slot];
            const float nv = nbvL[r], sv = svL[r];
            float s = 0.f;
            if (nv != 0.f) {
                float d = nsyL[m] + ws[OFF_CEB + (size_t)(k0 + r) * 90 + m];
                const float* hr = &hR[r * 100];
#pragma unroll 6
                for (int k = 0; k < 90; ++k) d += hr[k] * W_sync[k * 90 + m];
                s = nv * fmaxf(d, 0.f);
            }
            if (k0 + r == q) {
                const int nnb = nnbS;
                const float nsym = nsyL[m];
                for (int j = 0; j < nnb; ++j) s += nbw[j] * fmaxf(nsym + rfd[j][m], 0.f);
            }
            actb[slot][m] = 0.5f * s + 0.5f * sv * pvL[m];
        }
        __syncthreads();
        // C2: inf
        for (int idx = tid; idx < na * 90; idx += 512) {
            const int slot = idx / 90, m = idx - slot * 90;
            float d = baggL[m];
#pragma unroll 6
            for (int k = 0; k < 90; ++k) d += actb[slot][k] * W_agg[k * 90 + m];
            infb[slot][m] = fmaxf(d, 0.f);
        }
        __syncthreads();
        // C3: gi
        for (int idx = tid; idx < na * 270; idx += 512) {
            const int slot = idx / 270, c = idx - slot * 270;
            float d = biL[c];
#pragma unroll 6
            for (int k = 0; k < 90; ++k) d += infb[slot][k] * Wi_rnn[k * 270 + c];
            giL[slot * 273 + c] = d;
        }
        __syncthreads();
        // C4: gates (MFMA acc in registers)
#pragma unroll
        for (int ct = 0; ct < 3; ++ct) {
            const int m = cg * 48 + ct * 16 + lr;
            if (m < 90) {
                const float bhr = bhL[m], bhz = bhL[90 + m], bhg = bhL[180 + m];
#pragma unroll
                for (int r4 = 0; r4 < 4; ++r4) {
                    const int row = rt * 16 + 4 * lh + r4;
                    const int sraw = rowslotS[row];
                    const bool mine = (sraw < 0) ? (pass == 0) : (sraw >= e0p && sraw < e1p);
                    if (!mine) continue;
                    const float* gs = (sraw < 0) ? gi0L : &giL[(sraw - e0p) * 273];
                    const float rg = sigf(gs[m] + acc[0][ct][r4] + bhr);
                    const float zg = sigf(gs[90 + m] + acc[1][ct][r4] + bhz);
                    const float gg = tanhf_(gs[180 + m] + rg * (acc[2][ct][r4] + bhg));
                    const float hold = hR[row * 100 + m];
                    const float hn = (1.f - zg) * gg + zg * hold;
                    hR[row * 100 + m] = hn;
                    stOut[((size_t)(bb * KU + k0 + row)) * 90 + m] = hn;
                }
            }
        }
        __syncthreads();
    }

    // ================= out head (8 threads/row) =================
    {
        const int row = tid >> 3, j = tid & 7;
        const int m0 = j * 12;
        float p = 0.f;
#pragma unroll
        for (int mm = 0; mm < 12; ++mm) {
            const int m = m0 + mm;
            if (m < 90) p += hR[row * 100 + m] * woutL[m];
        }
#pragma unroll
        for (int o = 1; o < 8; o <<= 1) p += __shfl_xor(p, o);
        if (j == 0)
            out[(size_t)t * NB * KU + (size_t)bb * KU + k0 + row] = sigf(p + b_out[0]);
    }
}

extern "C" void kernel_launch(void* const* d_in, const int* in_sizes, int n_in,
                              void* d_out, int out_size, void* d_ws, size_t ws_size,
                              hipStream_t stream) {
    const int* questions = (const int*)d_in[0];
    const int* answers = (const int*)d_in[1];
    const float* response_emb = (const float*)d_in[2];
    const float* concept_emb = (const float*)d_in[3];
    const float* nb_adj = (const float*)d_in[4];
    const float* succ_adj = (const float*)d_in[5];
    const float* Wi_self = (const float*)d_in[6];
    const float* Wh_self = (const float*)d_in[7];
    const float* bi_self = (const float*)d_in[8];
    const float* bh_self = (const float*)d_in[9];
    const float* Wi_rnn = (const float*)d_in[10];
    const float* Wh_rnn = (const float*)d_in[11];
    const float* bi_rnn = (const float*)d_in[12];
    const float* bh_rnn = (const float*)d_in[13];
    const float* W_sync = (const float*)d_in[14];
    const float* b_sync = (const float*)d_in[15];
    const float* W_prop = (const float*)d_in[16];
    const float* b_prop = (const float*)d_in[17];
    const float* W_agg = (const float*)d_in[18];
    const float* b_agg = (const float*)d_in[19];
    const float* W_out = (const float*)d_in[20];
    const float* b_out = (const float*)d_in[21];

    float* out = (float*)d_out;
    float* stFinal = out + (size_t)NT * NB * KU;   // states region of d_out
    float* ws = (float*)d_ws;

    hipMemsetAsync(stFinal, 0, (size_t)NB * KU * 90 * sizeof(float), stream);
    skt_prep<<<132, 256, 0, stream>>>(concept_emb, W_sync, b_sync, Wi_rnn, Wh_rnn,
                                      bi_rnn, b_agg, ws);
    for (int t = 0; t < NT; ++t) {
        const float* sin = (t & 1) ? ws : stFinal;
        float* sout = (t & 1) ? stFinal : ws;
        skt_step<<<NB * 8, 512, 0, stream>>>(
            questions, answers, response_emb, concept_emb, nb_adj, succ_adj,
            Wi_self, Wh_self, bi_self, bh_self, Wi_rnn, bi_rnn, bh_rnn, b_agg,
            W_sync, W_prop, b_prop, W_agg, W_out, b_out,
            ws, sin, sout, out, t);
    }
}

// Round 9
// 1589.907 us; speedup vs baseline: 3.6539x; 2.1081x over previous
//
#include <hip/hip_runtime.h>

#define KU 512
#define NB 32
#define NT 64
#define TIL 64
#define SLOTS 16
#define NBMAX 40

// ---- ws float offsets ----
#define N_PONG   (KU * NB * 90)
#define OFF_CEB  (N_PONG)                  // ce_sync+b_sync [512][90] f32
#define OFF_GI0  (OFF_CEB + KU * 90)       // gi0 [272] f32
#define OFF_WHTF (OFF_GI0 + 288)           // ushort[3][6][3][64][8]  Wh frags   (27648 us)
#define OFF_SYF  (OFF_WHTF + 13824)        // ushort[6][3][64][8]     Wsync_low  (9216 us)
#define OFF_AGF  (OFF_SYF + 4608)          // ushort[6][3][64][8]     W_agg      (9216 us)
#define OFF_WIF  (OFF_AGF + 4608)          // ushort[17][3][64][8]    Wi_rnn     (26112 us)

typedef short bf16x8 __attribute__((ext_vector_type(8)));
typedef float f32x4 __attribute__((ext_vector_type(4)));

__device__ __forceinline__ float sigf(float x) { return 1.0f / (1.0f + __expf(-x)); }
__device__ __forceinline__ float tanhf_(float x) {
    float e = __expf(2.0f * x);
    return 1.0f - 2.0f / (e + 1.0f);
}
__device__ __forceinline__ unsigned short f2bf(float f) {
    union { float f; unsigned u; } v; v.f = f;
    unsigned r = v.u + 0x7FFFu + ((v.u >> 16) & 1u);
    return (unsigned short)(r >> 16);
}
__device__ __forceinline__ bf16x8 cvt8(const float* p) {
    const float4 a0 = *(const float4*)p;
    const float4 a1 = *(const float4*)(p + 4);
    union { bf16x8 v; unsigned short u[8]; } fr;
    fr.u[0] = f2bf(a0.x); fr.u[1] = f2bf(a0.y); fr.u[2] = f2bf(a0.z); fr.u[3] = f2bf(a0.w);
    fr.u[4] = f2bf(a1.x); fr.u[5] = f2bf(a1.y); fr.u[6] = f2bf(a1.z); fr.u[7] = f2bf(a1.w);
    return fr.v;
}

// ============ prep: ce_sync + gi0 + all bf16 weight fragments (once) ============
__global__ void skt_prep(const float* __restrict__ concept_emb, const float* __restrict__ W_sync,
                         const float* __restrict__ b_sync, const float* __restrict__ Wi_rnn,
                         const float* __restrict__ Wh_rnn, const float* __restrict__ bi_rnn,
                         const float* __restrict__ b_agg, const float* __restrict__ W_agg,
                         float* __restrict__ ws) {
    const int blk = blockIdx.x, tid = threadIdx.x;
    if (blk < 128) {                       // ceb[512][90] = b_sync + ce @ W_sync[180:270]
        for (int rr = 0; rr < 4; ++rr) {
            const int k = blk * 4 + rr;
            if (tid < 90) {
                float acc = b_sync[tid];
                for (int kk = 0; kk < 90; ++kk)
                    acc += concept_emb[k * 90 + kk] * W_sync[(180 + kk) * 90 + tid];
                ws[OFF_CEB + k * 90 + tid] = acc;
            }
        }
    } else if (blk < 131) {                // whtF[g][nb][kk][lane][i]
        const int g = blk - 128;
        unsigned short* p = (unsigned short*)(ws + OFF_WHTF);
        for (int idx = tid; idx < 6 * 3 * 64 * 8; idx += 256) {
            const int i = idx & 7, lane = (idx >> 3) & 63;
            const int rest = idx >> 9;
            const int kk = rest % 3, nb = rest / 3;
            const int n = nb * 16 + (lane & 15);
            const int k = kk * 32 + ((lane >> 4) << 3) + i;
            const float v = (n < 90 && k < 90) ? Wh_rnn[k * 270 + g * 90 + n] : 0.f;
            p[(size_t)g * 9216 + idx] = f2bf(v);
        }
    } else if (blk == 131) {               // gi0[272]
        for (int c = tid; c < 272; c += 256) {
            float acc = 0.f;
            if (c < 270) {
                acc = bi_rnn[c];
                for (int kk = 0; kk < 90; ++kk)
                    acc += fmaxf(b_agg[kk], 0.f) * Wi_rnn[kk * 270 + c];
            }
            ws[OFF_GI0 + c] = acc;
        }
    } else if (blk == 132) {               // syF: W_sync rows 0..89
        unsigned short* p = (unsigned short*)(ws + OFF_SYF);
        for (int idx = tid; idx < 9216; idx += 256) {
            const int i = idx & 7, lane = (idx >> 3) & 63;
            const int rest = idx >> 9;
            const int kk = rest % 3, nt = rest / 3;
            const int n = nt * 16 + (lane & 15);
            const int k = kk * 32 + ((lane >> 4) << 3) + i;
            p[idx] = f2bf((n < 90 && k < 90) ? W_sync[k * 90 + n] : 0.f);
        }
    } else if (blk == 133) {               // agF: W_agg
        unsigned short* p = (unsigned short*)(ws + OFF_AGF);
        for (int idx = tid; idx < 9216; idx += 256) {
            const int i = idx & 7, lane = (idx >> 3) & 63;
            const int rest = idx >> 9;
            const int kk = rest % 3, nt = rest / 3;
            const int n = nt * 16 + (lane & 15);
            const int k = kk * 32 + ((lane >> 4) << 3) + i;
            p[idx] = f2bf((n < 90 && k < 90) ? W_agg[k * 90 + n] : 0.f);
        }
    } else {                               // wiF: Wi_rnn (17 n-tiles), blk 134/135
        unsigned short* p = (unsigned short*)(ws + OFF_WIF);
        const int i0 = (blk - 134) * 13824;
        const int i1 = (blk == 134) ? 13824 : 26112;
        for (int idx = i0 + tid; idx < i1; idx += 256) {
            const int i = idx & 7, lane = (idx >> 3) & 63;
            const int rest = idx >> 9;
            const int kk = rest % 3, nt = rest / 3;
            const int n = nt * 16 + (lane & 15);
            const int k = kk * 32 + ((lane >> 4) << 3) + i;
            p[idx] = f2bf((n < 270 && k < 90) ? Wi_rnn[k * 270 + n] : 0.f);
        }
    }
}

// ============ merged per-step kernel: 256 blocks x 512 thr, TIL=64 ============
__global__ __launch_bounds__(512, 1) void skt_step(
    const int* __restrict__ qs, const int* __restrict__ as_,
    const float* __restrict__ response_emb, const float* __restrict__ concept_emb,
    const float* __restrict__ nb_adj, const float* __restrict__ succ_adj,
    const float* __restrict__ Wi_self, const float* __restrict__ Wh_self,
    const float* __restrict__ bi_self, const float* __restrict__ bh_self,
    const float* __restrict__ bi_rnn, const float* __restrict__ bh_rnn,
    const float* __restrict__ b_agg, const float* __restrict__ W_sync,
    const float* __restrict__ W_prop, const float* __restrict__ b_prop,
    const float* __restrict__ W_out, const float* __restrict__ b_out,
    float* __restrict__ ws, const float* __restrict__ stIn, float* __restrict__ stOut,
    float* __restrict__ out, int t) {
    __shared__ alignas(16) float hR[TIL * 100];
    __shared__ alignas(16) float hnb[NBMAX * 96];
    __shared__ alignas(16) float rfd[NBMAX * 92];
    __shared__ alignas(16) float giL[SLOTS * 273];
    __shared__ alignas(16) float actb[SLOTS * 96], infb[SLOTS * 96];
    __shared__ alignas(16) float giA[272], ghA[272];
    __shared__ alignas(16) float gi0L[273], biL[273], bhL[272];
    __shared__ alignas(16) float re[92], ssv[92], ceq[92], nsv[92], xprop[184];
    __shared__ alignas(16) float nsyL[92], pvL[92], baggL[92], woutL[92];
    __shared__ float nbw[NBMAX];
    __shared__ int nblist[NBMAX];
    __shared__ float nbvL[TIL], svL[TIL];
    __shared__ int rowslotS[TIL], listS[TIL];
    __shared__ int nactS, nnbS;

    const int tid = threadIdx.x;
    const int bb = blockIdx.x >> 3;
    const int k0 = (blockIdx.x & 7) * TIL;
    const int q = qs[bb * NT + t];
    const int a = as_[bb * NT + t];
    const bool owner = (q >= k0 && q < k0 + TIL);

    const int w8 = tid >> 6, lane = tid & 63;
    const int lr = lane & 15, lh = lane >> 4;
    const int rt = w8 & 3, cg = w8 >> 2;

    const unsigned short* whtF = (const unsigned short*)(ws + OFF_WHTF);
    const unsigned short* syF = (const unsigned short*)(ws + OFF_SYF);
    const unsigned short* agF = (const unsigned short*)(ws + OFF_AGF);
    const unsigned short* wiF = (const unsigned short*)(ws + OFF_WIF);

    // ================= B0: stage =================
    if (tid < 384) {                     // hR 64 x 50 float2 (cols 90..99 zero)
        for (int idx = tid; idx < TIL * 50; idx += 384) {
            const int row = idx / 50, c2 = idx - row * 50;
            float2 v = make_float2(0.f, 0.f);
            if (c2 < 45)
                v = ((const float2*)(stIn + ((size_t)(bb * KU + k0 + row)) * 90))[c2];
            *(float2*)&hR[row * 100 + 2 * c2] = v;
        }
    } else if (tid < 448) {              // wave 6: active-row scan
        const int l = tid - 384;
        const int kg = k0 + l;
        const float nv = nb_adj[(size_t)q * KU + kg];
        const float sv = succ_adj[(size_t)q * KU + kg];
        nbvL[l] = nv; svL[l] = sv;
        const bool act = (nv != 0.f) || (sv != 0.f) || (kg == q);
        const unsigned long long mb = __ballot(act);
        const int rank = (int)__popcll(mb & ((1ull << l) - 1ull));
        rowslotS[l] = act ? rank : -1;
        if (act) listS[rank] = l;
        if (l == 0) nactS = (int)__popcll(mb);
    } else {                             // wave 7: neighbor scan of q
        const int l = tid - 448;
        int base = 0;
        for (int ch = 0; ch < 8; ++ch) {
            const int kp = ch * 64 + l;
            const float nv = nb_adj[(size_t)q * KU + kp];
            const unsigned long long mb = __ballot(nv != 0.f);
            const int idx = base + (int)__popcll(mb & ((1ull << l) - 1ull));
            if (nv != 0.f && idx < NBMAX) { nblist[idx] = kp; nbw[idx] = nv; }
            base += (int)__popcll(mb);
        }
        if (l == 0) nnbS = (base < NBMAX) ? base : NBMAX;
    }
    for (int j = tid; j < 270; j += 512) {
        if (j < 90) re[j] = response_emb[(size_t)a * 90 + j];
        else if (j < 180) ssv[j - 90] = stIn[((size_t)(bb * KU + q)) * 90 + (j - 90)];
        else ceq[j - 180] = concept_emb[(size_t)q * 90 + (j - 180)];
    }
    for (int c = tid; c < 273; c += 512) {
        gi0L[c] = (c < 272) ? ws[OFF_GI0 + c] : 0.f;
        biL[c] = (c < 270) ? bi_rnn[c] : 0.f;
        if (c < 272) bhL[c] = (c < 270) ? bh_rnn[c] : 0.f;
    }
    for (int m = tid; m < 92; m += 512) {
        baggL[m] = (m < 90) ? b_agg[m] : 0.f;
        woutL[m] = (m < 90) ? W_out[m] : 0.f;
    }
    for (int i = tid; i < SLOTS * 12; i += 512) {     // actb/infb pad cols 90..95
        const int half = i >= SLOTS * 6;
        const int j = half ? i - SLOTS * 6 : i;
        const int slot = j / 6, c = 90 + (j - (j / 6) * 6);
        (half ? infb : actb)[slot * 96 + c] = 0.f;
    }
    __syncthreads();   // #B0

    // ================= B1: self-GRU matvecs (f32) | owner hnb gather | gh MFMA ==========
    if (tid < 270) {
        const int half = tid / 135;
        const int c2 = tid - half * 135;           // cols 2c2, 2c2+1
        const float* W = half ? Wh_self : Wi_self;
        const float* xv = half ? ssv : re;
        const float* bv = half ? bh_self : bi_self;
        float a0 = bv[2 * c2], a1 = bv[2 * c2 + 1];
#pragma unroll 15
        for (int k = 0; k < 90; ++k) {
            const float2 w = *(const float2*)&W[k * 270 + 2 * c2];
            const float x = xv[k];
            a0 += x * w.x; a1 += x * w.y;
        }
        float* dst = half ? ghA : giA;
        dst[2 * c2] = a0; dst[2 * c2 + 1] = a1;
    } else if (owner) {
        const int nnb = nnbS;
        for (int i = tid - 270; i < nnb * 48; i += 242) {
            const int j = i / 48, c2 = i - j * 48;
            float2 v = make_float2(0.f, 0.f);
            if (c2 < 45)
                v = ((const float2*)(stIn + ((size_t)(bb * KU + nblist[j])) * 90))[c2];
            *(float2*)&hnb[j * 96 + 2 * c2] = v;
        }
    }
    // gh MFMA (all waves): A = own hR rows (f32->bf16), B = whtF
    f32x4 acc[3][3];
#pragma unroll
    for (int g = 0; g < 3; ++g)
#pragma unroll
        for (int ct = 0; ct < 3; ++ct) acc[g][ct] = f32x4{0.f, 0.f, 0.f, 0.f};
    {
        bf16x8 afr[3];
        const float* ar = &hR[(rt * 16 + lr) * 100];
#pragma unroll
        for (int kk = 0; kk < 3; ++kk) afr[kk] = cvt8(ar + kk * 32 + lh * 8);
#pragma unroll
        for (int g = 0; g < 3; ++g) {
#pragma unroll
            for (int ct = 0; ct < 3; ++ct) {
                const int nb = cg * 3 + ct;
                const unsigned short* bp = whtF + (size_t)(g * 6 + nb) * 1536 + lane * 8;
                acc[g][ct] = __builtin_amdgcn_mfma_f32_16x16x32_bf16(
                    afr[0], *(const bf16x8*)(bp), acc[g][ct], 0, 0, 0);
                acc[g][ct] = __builtin_amdgcn_mfma_f32_16x16x32_bf16(
                    afr[1], *(const bf16x8*)(bp + 512), acc[g][ct], 0, 0, 0);
                acc[g][ct] = __builtin_amdgcn_mfma_f32_16x16x32_bf16(
                    afr[2], *(const bf16x8*)(bp + 1024), acc[g][ct], 0, 0, 0);
            }
        }
    }
    __syncthreads();   // #B1

    // ================= B2: next_self gates | owner rfd MFMA =================
    if (tid < 90) {
        const float r = sigf(giA[tid] + ghA[tid]);
        const float z = sigf(giA[90 + tid] + ghA[90 + tid]);
        const float g = tanhf_(giA[180 + tid] + r * ghA[180 + tid]);
        const float ns = (1.f - z) * g + z * ssv[tid];
        nsv[tid] = ns;
        xprop[tid] = ns - ssv[tid];
        xprop[90 + tid] = ceq[tid];
    }
    if (owner) {
        const int nnb = nnbS;
        const int mtc = (nnb + 15) >> 4;
        const int pairs = mtc * 6;
        for (int p = w8; p < pairs; p += 8) {
            const int mt = p / 6, nt = p - mt * 6;
            bf16x8 af[3];
            const int jrow = mt * 16 + lr;
            if (jrow < nnb) {
                const float* rp = &hnb[jrow * 96];
#pragma unroll
                for (int kk = 0; kk < 3; ++kk) af[kk] = cvt8(rp + kk * 32 + lh * 8);
            } else {
                const bf16x8 z = {0, 0, 0, 0, 0, 0, 0, 0};
                af[0] = z; af[1] = z; af[2] = z;
            }
            f32x4 d = f32x4{0.f, 0.f, 0.f, 0.f};
            const unsigned short* bp = syF + (size_t)nt * 1536 + lane * 8;
            d = __builtin_amdgcn_mfma_f32_16x16x32_bf16(af[0], *(const bf16x8*)(bp), d, 0, 0, 0);
            d = __builtin_amdgcn_mfma_f32_16x16x32_bf16(af[1], *(const bf16x8*)(bp + 512), d, 0, 0, 0);
            d = __builtin_amdgcn_mfma_f32_16x16x32_bf16(af[2], *(const bf16x8*)(bp + 1024), d, 0, 0, 0);
#pragma unroll
            for (int r4 = 0; r4 < 4; ++r4) {
                const int j = mt * 16 + lh * 4 + r4;
                const int m = nt * 16 + lr;
                if (j < nnb && m < 90)
                    rfd[j * 92 + m] = d[r4] + ws[OFF_CEB + (size_t)nblist[j] * 90 + m];
            }
        }
    }
    __syncthreads();   // #B2

    // ================= B3: nsync + pvec (f32, M=1) =================
    if (tid < 90) {
        float d = 0.f;
#pragma unroll 15
        for (int k = 0; k < 90; ++k) d += nsv[k] * W_sync[(90 + k) * 90 + tid];
        nsyL[tid] = d;
    } else if (tid < 180) {
        const int m = tid - 90;
        float d = b_prop[m];
#pragma unroll 20
        for (int k = 0; k < 180; ++k) d += xprop[k] * W_prop[k * 90 + m];
        pvL[m] = fmaxf(d, 0.f);
    }
    __syncthreads();   // #B3

    // ================= C: MFMA chains + gates (multi-pass) =================
    const int nact = nactS;
    const int npass0 = (nact + SLOTS - 1) / SLOTS;
    const int npass = (npass0 > 0) ? npass0 : 1;
    for (int pass = 0; pass < npass; ++pass) {
        const int e0p = pass * SLOTS;
        int e1p = e0p + SLOTS; if (e1p > nact) e1p = nact;
        const int na = e1p - e0p;

        // C1: act = 0.5*(nv*relu(nsy+ceb+h@Wsy) + isq*reflec) + 0.5*sv*pv
        if (w8 < 6 && na > 0) {
            const int nt = w8;
            bf16x8 af[3];
            if (lr < na) {
                const float* rp = &hR[listS[e0p + lr] * 100];
#pragma unroll
                for (int kk = 0; kk < 3; ++kk) af[kk] = cvt8(rp + kk * 32 + lh * 8);
            } else {
                const bf16x8 z = {0, 0, 0, 0, 0, 0, 0, 0};
                af[0] = z; af[1] = z; af[2] = z;
            }
            f32x4 d = f32x4{0.f, 0.f, 0.f, 0.f};
            const unsigned short* bp = syF + (size_t)nt * 1536 + lane * 8;
            d = __builtin_amdgcn_mfma_f32_16x16x32_bf16(af[0], *(const bf16x8*)(bp), d, 0, 0, 0);
            d = __builtin_amdgcn_mfma_f32_16x16x32_bf16(af[1], *(const bf16x8*)(bp + 512), d, 0, 0, 0);
            d = __builtin_amdgcn_mfma_f32_16x16x32_bf16(af[2], *(const bf16x8*)(bp + 1024), d, 0, 0, 0);
            const int m = nt * 16 + lr;
            if (m < 90) {
#pragma unroll
                for (int r4 = 0; r4 < 4; ++r4) {
                    const int slot = lh * 4 + r4;
                    if (slot >= na) continue;
                    const int r = listS[e0p + slot];
                    const float nv = nbvL[r], sv = svL[r];
                    float s = 0.f;
                    if (nv != 0.f)
                        s = nv * fmaxf(nsyL[m] + ws[OFF_CEB + (size_t)(k0 + r) * 90 + m] + d[r4], 0.f);
                    if (k0 + r == q) {
                        const int nnb = nnbS;
                        const float nsym = nsyL[m];
                        for (int j = 0; j < nnb; ++j)
                            s += nbw[j] * fmaxf(nsym + rfd[j * 92 + m], 0.f);
                    }
                    actb[slot * 96 + m] = 0.5f * s + 0.5f * sv * pvL[m];
                }
            }
        }
        __syncthreads();

        // C2: inf = relu(bagg + act @ W_agg)
        if (w8 < 6 && na > 0) {
            const int nt = w8;
            bf16x8 af[3];
            if (lr < na) {
                const float* rp = &actb[lr * 96];
#pragma unroll
                for (int kk = 0; kk < 3; ++kk) af[kk] = cvt8(rp + kk * 32 + lh * 8);
            } else {
                const bf16x8 z = {0, 0, 0, 0, 0, 0, 0, 0};
                af[0] = z; af[1] = z; af[2] = z;
            }
            f32x4 d = f32x4{0.f, 0.f, 0.f, 0.f};
            const unsigned short* bp = agF + (size_t)nt * 1536 + lane * 8;
            d = __builtin_amdgcn_mfma_f32_16x16x32_bf16(af[0], *(const bf16x8*)(bp), d, 0, 0, 0);
            d = __builtin_amdgcn_mfma_f32_16x16x32_bf16(af[1], *(const bf16x8*)(bp + 512), d, 0, 0, 0);
            d = __builtin_amdgcn_mfma_f32_16x16x32_bf16(af[2], *(const bf16x8*)(bp + 1024), d, 0, 0, 0);
            const int m = nt * 16 + lr;
            if (m < 90) {
#pragma unroll
                for (int r4 = 0; r4 < 4; ++r4) {
                    const int slot = lh * 4 + r4;
                    if (slot < na) infb[slot * 96 + m] = fmaxf(baggL[m] + d[r4], 0.f);
                }
            }
        }
        __syncthreads();

        // C3: gi = bi + inf @ Wi_rnn   (17 n-tiles over 8 waves)
        if (na > 0) {
            bf16x8 af[3];
            if (lr < na) {
                const float* rp = &infb[lr * 96];
#pragma unroll
                for (int kk = 0; kk < 3; ++kk) af[kk] = cvt8(rp + kk * 32 + lh * 8);
            } else {
                const bf16x8 z = {0, 0, 0, 0, 0, 0, 0, 0};
                af[0] = z; af[1] = z; af[2] = z;
            }
            for (int nt = w8; nt < 17; nt += 8) {
                f32x4 d = f32x4{0.f, 0.f, 0.f, 0.f};
                const unsigned short* bp = wiF + (size_t)nt * 1536 + lane * 8;
                d = __builtin_amdgcn_mfma_f32_16x16x32_bf16(af[0], *(const bf16x8*)(bp), d, 0, 0, 0);
                d = __builtin_amdgcn_mfma_f32_16x16x32_bf16(af[1], *(const bf16x8*)(bp + 512), d, 0, 0, 0);
                d = __builtin_amdgcn_mfma_f32_16x16x32_bf16(af[2], *(const bf16x8*)(bp + 1024), d, 0, 0, 0);
                const int c = nt * 16 + lr;
                if (c < 270) {
#pragma unroll
                    for (int r4 = 0; r4 < 4; ++r4) {
                        const int slot = lh * 4 + r4;
                        if (slot < na) giL[slot * 273 + c] = biL[c] + d[r4];
                    }
                }
            }
        }
        __syncthreads();

        // C4: gates (gh acc in registers)
#pragma unroll
        for (int ct = 0; ct < 3; ++ct) {
            const int m = cg * 48 + ct * 16 + lr;
            if (m < 90) {
                const float bhr = bhL[m], bhz = bhL[90 + m], bhg = bhL[180 + m];
#pragma unroll
                for (int r4 = 0; r4 < 4; ++r4) {
                    const int row = rt * 16 + 4 * lh + r4;
                    const int sraw = rowslotS[row];
                    const bool mine = (sraw < 0) ? (pass == 0) : (sraw >= e0p && sraw < e1p);
                    if (!mine) continue;
                    const float* gs = (sraw < 0) ? gi0L : &giL[(sraw - e0p) * 273];
                    const float rg = sigf(gs[m] + acc[0][ct][r4] + bhr);
                    const float zg = sigf(gs[90 + m] + acc[1][ct][r4] + bhz);
                    const float gg = tanhf_(gs[180 + m] + rg * (acc[2][ct][r4] + bhg));
                    const float hold = hR[row * 100 + m];
                    const float hn = (1.f - zg) * gg + zg * hold;
                    hR[row * 100 + m] = hn;
                    stOut[((size_t)(bb * KU + k0 + row)) * 90 + m] = hn;
                }
            }
        }
        __syncthreads();
    }

    // ================= out head (8 threads/row) =================
    {
        const int row = tid >> 3, j = tid & 7;
        const int m0 = j * 12;
        float p = 0.f;
#pragma unroll
        for (int mm = 0; mm < 12; ++mm) {
            const int m = m0 + mm;
            if (m < 90) p += hR[row * 100 + m] * woutL[m];
        }
#pragma unroll
        for (int o = 1; o < 8; o <<= 1) p += __shfl_xor(p, o);
        if (j == 0)
            out[(size_t)t * NB * KU + (size_t)bb * KU + k0 + row] = sigf(p + b_out[0]);
    }
}

extern "C" void kernel_launch(void* const* d_in, const int* in_sizes, int n_in,
                              void* d_out, int out_size, void* d_ws, size_t ws_size,
                              hipStream_t stream) {
    const int* questions = (const int*)d_in[0];
    const int* answers = (const int*)d_in[1];
    const float* response_emb = (const float*)d_in[2];
    const float* concept_emb = (const float*)d_in[3];
    const float* nb_adj = (const float*)d_in[4];
    const float* succ_adj = (const float*)d_in[5];
    const float* Wi_self = (const float*)d_in[6];
    const float* Wh_self = (const float*)d_in[7];
    const float* bi_self = (const float*)d_in[8];
    const float* bh_self = (const float*)d_in[9];
    const float* Wi_rnn = (const float*)d_in[10];
    const float* Wh_rnn = (const float*)d_in[11];
    const float* bi_rnn = (const float*)d_in[12];
    const float* bh_rnn = (const float*)d_in[13];
    const float* W_sync = (const float*)d_in[14];
    const float* b_sync = (const float*)d_in[15];
    const float* W_prop = (const float*)d_in[16];
    const float* b_prop = (const float*)d_in[17];
    const float* W_agg = (const float*)d_in[18];
    const float* b_agg = (const float*)d_in[19];
    const float* W_out = (const float*)d_in[20];
    const float* b_out = (const float*)d_in[21];

    float* out = (float*)d_out;
    float* stFinal = out + (size_t)NT * NB * KU;   // states region of d_out
    float* ws = (float*)d_ws;

    hipMemsetAsync(stFinal, 0, (size_t)NB * KU * 90 * sizeof(float), stream);
    skt_prep<<<136, 256, 0, stream>>>(concept_emb, W_sync, b_sync, Wi_rnn, Wh_rnn,
                                      bi_rnn, b_agg, W_agg, ws);
    for (int t = 0; t < NT; ++t) {
        const float* sin = (t & 1) ? ws : stFinal;
        float* sout = (t & 1) ? stFinal : ws;
        skt_step<<<NB * 8, 512, 0, stream>>>(
            questions, answers, response_emb, concept_emb, nb_adj, succ_adj,
            Wi_self, Wh_self, bi_self, bh_self, bi_rnn, bh_rnn, b_agg,
            W_sync, W_prop, b_prop, W_out, b_out,
            ws, sin, sout, out, t);
    }
}